// Round 1
// baseline (1941.679 us; speedup 1.0000x reference)
//
#include <hip/hip_runtime.h>

#define N_NODES 100000
#define N_EDGES 3200000
#define F_IN 128
#define HID 64
#define N_CLASS 40

// ---------------- degree count ----------------
__global__ __launch_bounds__(256) void k_deg(const int* __restrict__ col, int* __restrict__ deg) {
    int i = blockIdx.x * 256 + threadIdx.x;
    int stride = gridDim.x * 256;
    for (int e = i; e < N_EDGES; e += stride) {
        atomicAdd(&deg[col[e]], 1);
    }
}

// ---------------- dinv = rsqrt(deg + 1 self loop) ----------------
__global__ __launch_bounds__(256) void k_dinv(const int* __restrict__ deg, float* __restrict__ dinv) {
    int i = blockIdx.x * 256 + threadIdx.x;
    if (i < N_NODES) {
        dinv[i] = rsqrtf((float)deg[i] + 1.0f);
    }
}

// ---------------- h1 = x @ W1^T  (N x 128) @ (128 x 64) ----------------
__global__ __launch_bounds__(256) void k_gemm1(const float* __restrict__ x, const float* __restrict__ W1,
                                               float* __restrict__ h1) {
    __shared__ float w1t[F_IN * HID];   // transposed: w1t[k*64 + j] = W1[j*128 + k]  (32 KB)
    __shared__ float xs[4][F_IN];       // 4 rows of x (2 KB)
    int t = threadIdx.x;
    for (int i = t; i < HID * F_IN; i += 256) {
        int j = i >> 7, k = i & 127;
        w1t[k * HID + j] = W1[i];
    }
    int row0 = blockIdx.x * 4;
    for (int i = t; i < 4 * F_IN; i += 256) {
        int r = i >> 7, k = i & 127;
        int rr = row0 + r;
        xs[r][k] = (rr < N_NODES) ? x[(size_t)rr * F_IN + k] : 0.f;
    }
    __syncthreads();
    int r = t >> 6, j = t & 63;
    int rr = row0 + r;
    if (rr < N_NODES) {
        float acc = 0.f;
#pragma unroll
        for (int k = 0; k < F_IN; ++k) acc += xs[r][k] * w1t[k * HID + j];
        h1[(size_t)rr * HID + j] = acc;
    }
}

// ---------------- scatter layer 1: o1[col] += norm * h1[row], 64 feats ----------------
__global__ __launch_bounds__(256) void k_scatter1(const int* __restrict__ row, const int* __restrict__ col,
                                                  const float* __restrict__ dinv, const float* __restrict__ h1,
                                                  float* __restrict__ o1) {
    int wave = (blockIdx.x * 256 + threadIdx.x) >> 6;
    int lane = threadIdx.x & 63;
    int nwaves = gridDim.x * 4;
    for (int e = wave; e < N_EDGES; e += nwaves) {
        int r = row[e], c = col[e];
        float a = dinv[r] * dinv[c];
        atomicAdd(&o1[(size_t)c * HID + lane], a * h1[(size_t)r * HID + lane]);
    }
}

// ---------------- self loop + bias + relu (in place on o1) ----------------
__global__ __launch_bounds__(256) void k_relu(float* __restrict__ o1, const float* __restrict__ h1,
                                              const float* __restrict__ dinv, const float* __restrict__ b1) {
    int i = blockIdx.x * 256 + threadIdx.x;
    if (i < N_NODES * HID) {
        int node = i >> 6, f = i & 63;
        float d = dinv[node];
        float v = o1[i] + d * d * h1[i] + b1[f];
        o1[i] = v > 0.f ? v : 0.f;
    }
}

// ---------------- h2 = o1 @ W2^T  (N x 64) @ (64 x 40) ----------------
__global__ __launch_bounds__(256) void k_gemm2(const float* __restrict__ o1, const float* __restrict__ W2,
                                               float* __restrict__ h2) {
    __shared__ float w2t[HID * N_CLASS];  // w2t[k*40 + c] = W2[c*64 + k]  (10 KB)
    __shared__ float xs[4][HID];
    int t = threadIdx.x;
    for (int i = t; i < N_CLASS * HID; i += 256) {
        int c = i >> 6, k = i & 63;
        w2t[k * N_CLASS + c] = W2[i];
    }
    int row0 = blockIdx.x * 4;
    {
        int r = t >> 6, k = t & 63;
        int rr = row0 + r;
        xs[r][k] = (rr < N_NODES) ? o1[(size_t)rr * HID + k] : 0.f;
    }
    __syncthreads();
    int r = t >> 6, c = t & 63;
    int rr = row0 + r;
    if (rr < N_NODES && c < N_CLASS) {
        float acc = 0.f;
#pragma unroll
        for (int k = 0; k < HID; ++k) acc += xs[r][k] * w2t[k * N_CLASS + c];
        h2[(size_t)rr * N_CLASS + c] = acc;
    }
}

// ---------------- scatter layer 2: xo[col] += norm * h2[row], 40 feats ----------------
__global__ __launch_bounds__(256) void k_scatter2(const int* __restrict__ row, const int* __restrict__ col,
                                                  const float* __restrict__ dinv, const float* __restrict__ h2,
                                                  float* __restrict__ xo) {
    int wave = (blockIdx.x * 256 + threadIdx.x) >> 6;
    int lane = threadIdx.x & 63;
    int nwaves = gridDim.x * 4;
    for (int e = wave; e < N_EDGES; e += nwaves) {
        int r = row[e], c = col[e];
        float a = dinv[r] * dinv[c];
        if (lane < N_CLASS) {
            atomicAdd(&xo[(size_t)c * N_CLASS + lane], a * h2[(size_t)r * N_CLASS + lane]);
        }
    }
}

// ---------------- self loop + bias + softmax/logsoftmax/argmax ----------------
__global__ __launch_bounds__(256) void k_softmax(const float* __restrict__ xo, const float* __restrict__ h2,
                                                 const float* __restrict__ dinv, const float* __restrict__ b2,
                                                 float* __restrict__ out, int* __restrict__ pred) {
    int i = blockIdx.x * 256 + threadIdx.x;
    if (i >= N_NODES) return;
    float d = dinv[i];
    float d2 = d * d;
    float v[N_CLASS];
    float m = -1e30f;
    int am = 0;
#pragma unroll
    for (int c = 0; c < N_CLASS; ++c) {
        float t = xo[(size_t)i * N_CLASS + c] + d2 * h2[(size_t)i * N_CLASS + c] + b2[c];
        v[c] = t;
        if (t > m) { m = t; am = c; }
    }
    float s = 0.f;
#pragma unroll
    for (int c = 0; c < N_CLASS; ++c) s += expf(v[c] - m);
    float ls = logf(s);
    float* logp = out;
    float* p = out + (size_t)N_NODES * N_CLASS;
#pragma unroll
    for (int c = 0; c < N_CLASS; ++c) {
        float lp = (v[c] - m) - ls;
        logp[(size_t)i * N_CLASS + c] = lp;
        p[(size_t)i * N_CLASS + c] = expf(lp);
    }
    pred[i] = am;
}

// ---------------- ratio: mean over original edges ----------------
__global__ __launch_bounds__(256) void k_ratio(const int* __restrict__ row, const int* __restrict__ col,
                                               const int* __restrict__ y, const int* __restrict__ pred,
                                               unsigned int* __restrict__ cnt) {
    int i = blockIdx.x * 256 + threadIdx.x;
    int stride = gridDim.x * 256;
    unsigned int local = 0;
    for (int e = i; e < N_EDGES; e += stride) {
        int r = row[e], c = col[e];
        bool sp = (pred[r] == pred[c]);
        bool sy = (y[r] == y[c]);
        local += (sp == sy) ? 1u : 0u;
    }
    if (local) atomicAdd(cnt, local);
}

__global__ void k_fin(const unsigned int* __restrict__ cnt, float* __restrict__ out) {
    out[0] = (float)(*cnt) / (float)N_EDGES;
}

extern "C" void kernel_launch(void* const* d_in, const int* in_sizes, int n_in,
                              void* d_out, int out_size, void* d_ws, size_t ws_size,
                              hipStream_t stream) {
    const float* x  = (const float*)d_in[0];
    const int*   ei = (const int*)d_in[1];
    const int*   y  = (const int*)d_in[2];
    const float* W1 = (const float*)d_in[3];
    const float* b1 = (const float*)d_in[4];
    const float* W2 = (const float*)d_in[5];
    const float* b2 = (const float*)d_in[6];

    const int* row = ei;             // edge_index[0]
    const int* col = ei + N_EDGES;   // edge_index[1]

    float* ws = (float*)d_ws;
    // workspace layout (floats)
    float* h1   = ws;                         // N*64
    float* o1   = ws + 6400000;               // N*64
    float* h2   = ws + 12800000;              // N*40
    float* xo   = ws + 16800000;              // N*40
    float* dinv = ws + 20800000;              // N
    int*   deg  = (int*)(ws + 20900000);      // N
    int*   pred = (int*)(ws + 21000000);      // N
    unsigned int* cnt = (unsigned int*)(ws + 21100000);  // 1

    float* out = (float*)d_out;   // logp [N*40], p [N*40], ratio [1]

    // zero accumulators (harness does not re-poison between replays)
    hipMemsetAsync(deg, 0, (size_t)N_NODES * 4, stream);
    hipMemsetAsync(o1, 0, (size_t)N_NODES * HID * 4, stream);
    hipMemsetAsync(xo, 0, (size_t)N_NODES * N_CLASS * 4, stream);
    hipMemsetAsync(cnt, 0, 4, stream);

    k_deg<<<2048, 256, 0, stream>>>(col, deg);
    k_dinv<<<(N_NODES + 255) / 256, 256, 0, stream>>>(deg, dinv);
    k_gemm1<<<(N_NODES + 3) / 4, 256, 0, stream>>>(x, W1, h1);
    k_scatter1<<<4096, 256, 0, stream>>>(row, col, dinv, h1, o1);
    k_relu<<<(N_NODES * HID + 255) / 256, 256, 0, stream>>>(o1, h1, dinv, b1);
    k_gemm2<<<(N_NODES + 3) / 4, 256, 0, stream>>>(o1, W2, h2);
    k_scatter2<<<4096, 256, 0, stream>>>(row, col, dinv, h2, xo);
    k_softmax<<<(N_NODES + 255) / 256, 256, 0, stream>>>(xo, h2, dinv, b2, out, pred);
    k_ratio<<<2048, 256, 0, stream>>>(row, col, y, pred, cnt);
    k_fin<<<1, 1, 0, stream>>>(cnt, out + (size_t)2 * N_NODES * N_CLASS);
}

// Round 4
// 1693.360 us; speedup vs baseline: 1.1466x; 1.1466x over previous
//
#include <hip/hip_runtime.h>

#define N_NODES 100000
#define N_EDGES 3200000
#define F_IN 128
#define HID 64
#define N_CLASS 40

// ---------------- degree histogram over col ----------------
__global__ __launch_bounds__(256) void k_deg(const int* __restrict__ col, int* __restrict__ deg) {
    int i = blockIdx.x * 256 + threadIdx.x;
    int stride = gridDim.x * 256;
    for (int e = i; e < N_EDGES; e += stride) {
        atomicAdd(&deg[col[e]], 1);
    }
}

// ---------------- single-block scan: offsets, cursor, dinv ----------------
__global__ __launch_bounds__(1024) void k_scan(const int* __restrict__ deg, int* __restrict__ off,
                                               int* __restrict__ cursor, float* __restrict__ dinv) {
    __shared__ int sums[1024];
    int t = threadIdx.x;
    const int CHUNK = (N_NODES + 1023) / 1024;  // 98
    int lo = t * CHUNK;
    int hi = lo + CHUNK; if (hi > N_NODES) hi = N_NODES;
    int s = 0;
    for (int i = lo; i < hi; ++i) s += deg[i];
    sums[t] = s;
    __syncthreads();
    for (int d = 1; d < 1024; d <<= 1) {
        int other = (t >= d) ? sums[t - d] : 0;
        __syncthreads();
        sums[t] += other;
        __syncthreads();
    }
    int run = sums[t] - s;  // exclusive prefix of this chunk
    for (int i = lo; i < hi; ++i) {
        off[i] = run;
        cursor[i] = run;
        run += deg[i];
        dinv[i] = rsqrtf((float)deg[i] + 1.0f);  // +1 self loop
    }
}

// ---------------- bucket fill: srow sorted by col ----------------
__global__ __launch_bounds__(256) void k_fill(const int* __restrict__ row, const int* __restrict__ col,
                                              int* __restrict__ cursor, int* __restrict__ srow) {
    int i = blockIdx.x * 256 + threadIdx.x;
    int stride = gridDim.x * 256;
    for (int e = i; e < N_EDGES; e += stride) {
        int c = col[e];
        int pos = atomicAdd(&cursor[c], 1);
        srow[pos] = row[e];
    }
}

// ---------------- h1 = x @ W1^T  (N x 128) @ (128 x 64) ----------------
__global__ __launch_bounds__(256) void k_gemm1(const float* __restrict__ x, const float* __restrict__ W1,
                                               float* __restrict__ h1) {
    __shared__ float w1t[F_IN * HID];   // w1t[k*64 + j] = W1[j*128 + k]  (32 KB)
    __shared__ float xs[4][F_IN];       // 4 rows of x (2 KB)
    int t = threadIdx.x;
    for (int i = t; i < HID * F_IN; i += 256) {
        int j = i >> 7, k = i & 127;
        w1t[k * HID + j] = W1[i];
    }
    int row0 = blockIdx.x * 4;
    for (int i = t; i < 4 * F_IN; i += 256) {
        int r = i >> 7, k = i & 127;
        int rr = row0 + r;
        xs[r][k] = (rr < N_NODES) ? x[(size_t)rr * F_IN + k] : 0.f;
    }
    __syncthreads();
    int r = t >> 6, j = t & 63;
    int rr = row0 + r;
    if (rr < N_NODES) {
        float acc = 0.f;
#pragma unroll
        for (int k = 0; k < F_IN; ++k) acc += xs[r][k] * w1t[k * HID + j];
        h1[(size_t)rr * HID + j] = acc;
    }
}

// ---------------- layer-1 aggregation (gather), fused self-loop+bias+relu ----------------
__global__ __launch_bounds__(256) void k_agg1(const int* __restrict__ off, const int* __restrict__ deg,
                                              const int* __restrict__ srow, const float* __restrict__ dinv,
                                              const float* __restrict__ h1, const float* __restrict__ b1,
                                              float* __restrict__ o1) {
    int node = (blockIdx.x * 256 + threadIdx.x) >> 6;
    int lane = threadIdx.x & 63;
    if (node >= N_NODES) return;
    int start = off[node];
    int end = start + deg[node];
    float acc = 0.f;
#pragma unroll 4
    for (int j = start; j < end; ++j) {
        int r = srow[j];
        acc += dinv[r] * h1[(size_t)r * HID + lane];
    }
    float dc = dinv[node];
    float v = dc * acc + dc * dc * h1[(size_t)node * HID + lane] + b1[lane];
    o1[(size_t)node * HID + lane] = v > 0.f ? v : 0.f;
}

// ---------------- h2 = o1 @ W2^T  (N x 64) @ (64 x 40) ----------------
__global__ __launch_bounds__(256) void k_gemm2(const float* __restrict__ o1, const float* __restrict__ W2,
                                               float* __restrict__ h2) {
    __shared__ float w2t[HID * N_CLASS];  // w2t[k*40 + c] = W2[c*64 + k]
    __shared__ float xs[4][HID];
    int t = threadIdx.x;
    for (int i = t; i < N_CLASS * HID; i += 256) {
        int c = i >> 6, k = i & 63;
        w2t[k * N_CLASS + c] = W2[i];
    }
    int row0 = blockIdx.x * 4;
    {
        int r = t >> 6, k = t & 63;
        int rr = row0 + r;
        xs[r][k] = (rr < N_NODES) ? o1[(size_t)rr * HID + k] : 0.f;
    }
    __syncthreads();
    int r = t >> 6, c = t & 63;
    int rr = row0 + r;
    if (rr < N_NODES && c < N_CLASS) {
        float acc = 0.f;
#pragma unroll
        for (int k = 0; k < HID; ++k) acc += xs[r][k] * w2t[k * N_CLASS + c];
        h2[(size_t)rr * N_CLASS + c] = acc;
    }
}

// ---------------- layer-2 aggregation + softmax/logsoftmax/argmax, fused ----------------
__global__ __launch_bounds__(256) void k_agg2(const int* __restrict__ off, const int* __restrict__ deg,
                                              const int* __restrict__ srow, const float* __restrict__ dinv,
                                              const float* __restrict__ h2, const float* __restrict__ b2,
                                              float* __restrict__ out, int* __restrict__ pred) {
    int node = (blockIdx.x * 256 + threadIdx.x) >> 6;
    int lane = threadIdx.x & 63;
    if (node >= N_NODES) return;
    int start = off[node];
    int end = start + deg[node];
    bool act = lane < N_CLASS;
    float acc = 0.f;
#pragma unroll 4
    for (int j = start; j < end; ++j) {
        int r = srow[j];
        if (act) acc += dinv[r] * h2[(size_t)r * N_CLASS + lane];
    }
    float dc = dinv[node];
    float v = -1e30f;
    if (act) {
        v = dc * acc + dc * dc * h2[(size_t)node * N_CLASS + lane] + b2[lane];
    }
    // wave-wide max
    float m = v;
#pragma unroll
    for (int k = 1; k < 64; k <<= 1) {
        float o = __shfl_xor(m, k);
        m = o > m ? o : m;
    }
    // wave-wide sum of exp
    float sv = act ? expf(v - m) : 0.f;
    float s = sv;
#pragma unroll
    for (int k = 1; k < 64; k <<= 1) s += __shfl_xor(s, k);
    float ls = logf(s);
    // argmax (first occurrence)
    float av = v;
    int ai = act ? lane : 64;
#pragma unroll
    for (int k = 1; k < 64; k <<= 1) {
        float ov = __shfl_xor(av, k);
        int oi = __shfl_xor(ai, k);
        if (ov > av || (ov == av && oi < ai)) { av = ov; ai = oi; }
    }
    if (act) {
        float lp = (v - m) - ls;
        float* logp = out;
        float* p = out + (size_t)N_NODES * N_CLASS;
        logp[(size_t)node * N_CLASS + lane] = lp;
        p[(size_t)node * N_CLASS + lane] = expf(lp);
    }
    if (lane == 0) pred[node] = ai;
}

// ---------------- ratio over original edges ----------------
__global__ __launch_bounds__(256) void k_ratio(const int* __restrict__ row, const int* __restrict__ col,
                                               const int* __restrict__ y, const int* __restrict__ pred,
                                               unsigned int* __restrict__ cnt) {
    int i = blockIdx.x * 256 + threadIdx.x;
    int stride = gridDim.x * 256;
    unsigned int local = 0;
    for (int e = i; e < N_EDGES; e += stride) {
        int r = row[e], c = col[e];
        bool sp = (pred[r] == pred[c]);
        bool sy = (y[r] == y[c]);
        local += (sp == sy) ? 1u : 0u;
    }
    if (local) atomicAdd(cnt, local);
}

__global__ void k_fin(const unsigned int* __restrict__ cnt, float* __restrict__ out) {
    out[0] = (float)(*cnt) / (float)N_EDGES;
}

extern "C" void kernel_launch(void* const* d_in, const int* in_sizes, int n_in,
                              void* d_out, int out_size, void* d_ws, size_t ws_size,
                              hipStream_t stream) {
    const float* x  = (const float*)d_in[0];
    const int*   ei = (const int*)d_in[1];
    const int*   y  = (const int*)d_in[2];
    const float* W1 = (const float*)d_in[3];
    const float* b1 = (const float*)d_in[4];
    const float* W2 = (const float*)d_in[5];
    const float* b2 = (const float*)d_in[6];

    const int* row = ei;             // edge_index[0]
    const int* col = ei + N_EDGES;   // edge_index[1]

    float* ws = (float*)d_ws;
    // workspace layout (float-sized slots)
    float* h1     = ws;                          // 6,400,000
    float* o1     = ws + 6400000;                // 6,400,000
    float* h2     = ws + 12800000;               // 4,000,000
    float* dinv   = ws + 16800000;               // 100,000
    int*   deg    = (int*)(ws + 16900000);       // 100,000
    int*   off    = (int*)(ws + 17000000);       // 100,000
    int*   cursor = (int*)(ws + 17100000);       // 100,000
    int*   srow   = (int*)(ws + 17200000);       // 3,200,000
    int*   pred   = (int*)(ws + 20400000);       // 100,000
    unsigned int* cnt = (unsigned int*)(ws + 20500000);

    float* out = (float*)d_out;   // logp [N*40], p [N*40], ratio [1]

    hipMemsetAsync(deg, 0, (size_t)N_NODES * 4, stream);
    hipMemsetAsync(cnt, 0, 4, stream);

    k_deg<<<2048, 256, 0, stream>>>(col, deg);
    k_scan<<<1, 1024, 0, stream>>>(deg, off, cursor, dinv);
    k_fill<<<2048, 256, 0, stream>>>(row, col, cursor, srow);
    k_gemm1<<<(N_NODES + 3) / 4, 256, 0, stream>>>(x, W1, h1);
    k_agg1<<<(N_NODES * 64 + 255) / 256, 256, 0, stream>>>(off, deg, srow, dinv, h1, b1, o1);
    k_gemm2<<<(N_NODES + 3) / 4, 256, 0, stream>>>(o1, W2, h2);
    k_agg2<<<(N_NODES * 64 + 255) / 256, 256, 0, stream>>>(off, deg, srow, dinv, h2, b2, out, pred);
    k_ratio<<<2048, 256, 0, stream>>>(row, col, y, pred, cnt);
    k_fin<<<1, 1, 0, stream>>>(cnt, out + (size_t)2 * N_NODES * N_CLASS);
}

// Round 5
// 1367.833 us; speedup vs baseline: 1.4195x; 1.2380x over previous
//
#include <hip/hip_runtime.h>

#define N_NODES 100000
#define N_EDGES 3200000
#define F_IN 128
#define HID 64
#define N_CLASS 40

// ---------------- degree histogram over col ----------------
__global__ __launch_bounds__(256) void k_deg(const int* __restrict__ col, int* __restrict__ deg) {
    int i = blockIdx.x * 256 + threadIdx.x;
    int stride = gridDim.x * 256;
    for (int e = i; e < N_EDGES; e += stride) {
        atomicAdd(&deg[col[e]], 1);
    }
}

// ---------------- single-block scan: offsets, cursor, dinv ----------------
__global__ __launch_bounds__(1024) void k_scan(const int* __restrict__ deg, int* __restrict__ off,
                                               int* __restrict__ cursor, float* __restrict__ dinv) {
    __shared__ int sums[1024];
    int t = threadIdx.x;
    const int CHUNK = (N_NODES + 1023) / 1024;  // 98
    int lo = t * CHUNK;
    int hi = lo + CHUNK; if (hi > N_NODES) hi = N_NODES;
    int s = 0;
    for (int i = lo; i < hi; ++i) s += deg[i];
    sums[t] = s;
    __syncthreads();
    for (int d = 1; d < 1024; d <<= 1) {
        int other = (t >= d) ? sums[t - d] : 0;
        __syncthreads();
        sums[t] += other;
        __syncthreads();
    }
    int run = sums[t] - s;  // exclusive prefix of this chunk
    for (int i = lo; i < hi; ++i) {
        off[i] = run;
        cursor[i] = run;
        run += deg[i];
        dinv[i] = rsqrtf((float)deg[i] + 1.0f);  // +1 self loop
    }
}

// ---------------- bucket fill: srow sorted by col ----------------
__global__ __launch_bounds__(256) void k_fill(const int* __restrict__ row, const int* __restrict__ col,
                                              int* __restrict__ cursor, int* __restrict__ srow) {
    int i = blockIdx.x * 256 + threadIdx.x;
    int stride = gridDim.x * 256;
    for (int e = i; e < N_EDGES; e += stride) {
        int c = col[e];
        int pos = atomicAdd(&cursor[c], 1);
        srow[pos] = row[e];
    }
}

// ---------------- tiled dense GEMM: O[N][C] = X[N][K] @ W[C][K]^T ----------------
// W staged once per block (padded +4 floats per row: lane-consecutive b128 reads
// are 16B apart -> conflict-free). Block owns ROWS_PB rows, chunks of 32 staged
// via coalesced float4. Thread = 1 col x 8 rows; x reads are wave-broadcast.
template<int K, int C, int ROWS_PB>
__global__ __launch_bounds__(256) void k_gemm(const float* __restrict__ X, const float* __restrict__ W,
                                              float* __restrict__ O) {
    constexpr int PK = K + 4;
    __shared__ float ws[C * PK];
    __shared__ float xs[32 * PK];
    int t = threadIdx.x;
    // stage W (C*K floats) as float4, conflict-free writes
    for (int i4 = t; i4 < C * K / 4; i4 += 256) {
        int j = i4 / (K / 4);
        int k4 = i4 % (K / 4);
        float4 v = ((const float4*)W)[i4];
        *(float4*)&ws[j * PK + k4 * 4] = v;
    }
    int j = t & 63;
    int r0 = (t >> 6) * 8;   // 8 rows per thread, 4 slots cover 32
    int rowbase = blockIdx.x * ROWS_PB;
    for (int chunk = 0; chunk < ROWS_PB; chunk += 32) {
        int cb = rowbase + chunk;
        __syncthreads();   // protect xs (and ws on first iter)
        for (int i4 = t; i4 < 32 * K / 4; i4 += 256) {
            int r = i4 / (K / 4);
            int k4 = i4 % (K / 4);
            int rr = cb + r;
            float4 v = make_float4(0.f, 0.f, 0.f, 0.f);
            if (rr < N_NODES) v = ((const float4*)X)[(size_t)rr * (K / 4) + k4];
            *(float4*)&xs[r * PK + k4 * 4] = v;
        }
        __syncthreads();
        if (j < C) {
            float acc[8] = {0.f, 0.f, 0.f, 0.f, 0.f, 0.f, 0.f, 0.f};
            for (int k4 = 0; k4 < K / 4; ++k4) {
                float4 wv = *(const float4*)&ws[j * PK + k4 * 4];
#pragma unroll
                for (int r = 0; r < 8; ++r) {
                    float4 xv = *(const float4*)&xs[(r0 + r) * PK + k4 * 4];
                    acc[r] += xv.x * wv.x + xv.y * wv.y + xv.z * wv.z + xv.w * wv.w;
                }
            }
#pragma unroll
            for (int r = 0; r < 8; ++r) {
                int rr = cb + r0 + r;
                if (rr < N_NODES) O[(size_t)rr * C + j] = acc[r];
            }
        }
    }
}

// ---------------- layer-1 aggregation (gather), fused self-loop+bias+relu ----------------
__global__ __launch_bounds__(256) void k_agg1(const int* __restrict__ off, const int* __restrict__ deg,
                                              const int* __restrict__ srow, const float* __restrict__ dinv,
                                              const float* __restrict__ h1, const float* __restrict__ b1,
                                              float* __restrict__ o1) {
    int node = (blockIdx.x * 256 + threadIdx.x) >> 6;
    int lane = threadIdx.x & 63;
    if (node >= N_NODES) return;
    int start = off[node];
    int end = start + deg[node];
    float acc = 0.f;
#pragma unroll 4
    for (int j = start; j < end; ++j) {
        int r = srow[j];
        acc += dinv[r] * h1[(size_t)r * HID + lane];
    }
    float dc = dinv[node];
    float v = dc * acc + dc * dc * h1[(size_t)node * HID + lane] + b1[lane];
    o1[(size_t)node * HID + lane] = v > 0.f ? v : 0.f;
}

// ---------------- layer-2 aggregation + softmax/logsoftmax/argmax, fused ----------------
__global__ __launch_bounds__(256) void k_agg2(const int* __restrict__ off, const int* __restrict__ deg,
                                              const int* __restrict__ srow, const float* __restrict__ dinv,
                                              const float* __restrict__ h2, const float* __restrict__ b2,
                                              float* __restrict__ out, int* __restrict__ pred) {
    int node = (blockIdx.x * 256 + threadIdx.x) >> 6;
    int lane = threadIdx.x & 63;
    if (node >= N_NODES) return;
    int start = off[node];
    int end = start + deg[node];
    bool act = lane < N_CLASS;
    float acc = 0.f;
#pragma unroll 4
    for (int j = start; j < end; ++j) {
        int r = srow[j];
        if (act) acc += dinv[r] * h2[(size_t)r * N_CLASS + lane];
    }
    float dc = dinv[node];
    float v = -1e30f;
    if (act) {
        v = dc * acc + dc * dc * h2[(size_t)node * N_CLASS + lane] + b2[lane];
    }
    // wave-wide max
    float m = v;
#pragma unroll
    for (int k = 1; k < 64; k <<= 1) {
        float o = __shfl_xor(m, k);
        m = o > m ? o : m;
    }
    // wave-wide sum of exp
    float sv = act ? expf(v - m) : 0.f;
    float s = sv;
#pragma unroll
    for (int k = 1; k < 64; k <<= 1) s += __shfl_xor(s, k);
    float ls = logf(s);
    // argmax (first occurrence)
    float av = v;
    int ai = act ? lane : 64;
#pragma unroll
    for (int k = 1; k < 64; k <<= 1) {
        float ov = __shfl_xor(av, k);
        int oi = __shfl_xor(ai, k);
        if (ov > av || (ov == av && oi < ai)) { av = ov; ai = oi; }
    }
    if (act) {
        float lp = (v - m) - ls;
        float* logp = out;
        float* p = out + (size_t)N_NODES * N_CLASS;
        logp[(size_t)node * N_CLASS + lane] = lp;
        p[(size_t)node * N_CLASS + lane] = expf(lp);
    }
    if (lane == 0) pred[node] = ai;
}

// ---------------- ratio over original edges ----------------
__global__ __launch_bounds__(256) void k_ratio(const int* __restrict__ row, const int* __restrict__ col,
                                               const int* __restrict__ y, const int* __restrict__ pred,
                                               unsigned int* __restrict__ cnt) {
    int i = blockIdx.x * 256 + threadIdx.x;
    int stride = gridDim.x * 256;
    unsigned int local = 0;
    for (int e = i; e < N_EDGES; e += stride) {
        int r = row[e], c = col[e];
        bool sp = (pred[r] == pred[c]);
        bool sy = (y[r] == y[c]);
        local += (sp == sy) ? 1u : 0u;
    }
    if (local) atomicAdd(cnt, local);
}

__global__ void k_fin(const unsigned int* __restrict__ cnt, float* __restrict__ out) {
    out[0] = (float)(*cnt) / (float)N_EDGES;
}

extern "C" void kernel_launch(void* const* d_in, const int* in_sizes, int n_in,
                              void* d_out, int out_size, void* d_ws, size_t ws_size,
                              hipStream_t stream) {
    const float* x  = (const float*)d_in[0];
    const int*   ei = (const int*)d_in[1];
    const int*   y  = (const int*)d_in[2];
    const float* W1 = (const float*)d_in[3];
    const float* b1 = (const float*)d_in[4];
    const float* W2 = (const float*)d_in[5];
    const float* b2 = (const float*)d_in[6];

    const int* row = ei;             // edge_index[0]
    const int* col = ei + N_EDGES;   // edge_index[1]

    float* ws = (float*)d_ws;
    // workspace layout (float-sized slots)
    float* h1     = ws;                          // 6,400,000
    float* o1     = ws + 6400000;                // 6,400,000
    float* h2     = ws + 12800000;               // 4,000,000
    float* dinv   = ws + 16800000;               // 100,000
    int*   deg    = (int*)(ws + 16900000);       // 100,000
    int*   off    = (int*)(ws + 17000000);       // 100,000
    int*   cursor = (int*)(ws + 17100000);       // 100,000
    int*   srow   = (int*)(ws + 17200000);       // 3,200,000
    int*   pred   = (int*)(ws + 20400000);       // 100,000
    unsigned int* cnt = (unsigned int*)(ws + 20500000);

    float* out = (float*)d_out;   // logp [N*40], p [N*40], ratio [1]

    hipMemsetAsync(deg, 0, (size_t)N_NODES * 4, stream);
    hipMemsetAsync(cnt, 0, 4, stream);

    const int GEMM_GRID = (N_NODES + 127) / 128;   // 782 blocks, 128 rows each

    k_deg<<<2048, 256, 0, stream>>>(col, deg);
    k_scan<<<1, 1024, 0, stream>>>(deg, off, cursor, dinv);
    k_fill<<<2048, 256, 0, stream>>>(row, col, cursor, srow);
    k_gemm<F_IN, HID, 128><<<GEMM_GRID, 256, 0, stream>>>(x, W1, h1);
    k_agg1<<<(N_NODES * 64 + 255) / 256, 256, 0, stream>>>(off, deg, srow, dinv, h1, b1, o1);
    k_gemm<HID, N_CLASS, 128><<<GEMM_GRID, 256, 0, stream>>>(o1, W2, h2);
    k_agg2<<<(N_NODES * 64 + 255) / 256, 256, 0, stream>>>(off, deg, srow, dinv, h2, b2, out, pred);
    k_ratio<<<2048, 256, 0, stream>>>(row, col, y, pred, cnt);
    k_fin<<<1, 1, 0, stream>>>(cnt, out + (size_t)2 * N_NODES * N_CLASS);
}

// Round 6
// 1338.888 us; speedup vs baseline: 1.4502x; 1.0216x over previous
//
#include <hip/hip_runtime.h>
#include <hip/hip_fp16.h>

#define N_NODES 100000
#define N_EDGES 3200000
#define F_IN 128
#define HID 64
#define N_CLASS 40

// ---------------- degree histogram over col ----------------
__global__ __launch_bounds__(256) void k_deg(const int* __restrict__ col, int* __restrict__ deg) {
    int i = blockIdx.x * 256 + threadIdx.x;
    int stride = gridDim.x * 256;
    for (int e = i; e < N_EDGES; e += stride) {
        atomicAdd(&deg[col[e]], 1);
    }
}

// ---------------- single-block scan: offsets, cursor, dinv ----------------
__global__ __launch_bounds__(1024) void k_scan(const int* __restrict__ deg, int* __restrict__ off,
                                               int* __restrict__ cursor, float* __restrict__ dinv) {
    __shared__ int sums[1024];
    int t = threadIdx.x;
    const int CHUNK = (N_NODES + 1023) / 1024;  // 98
    int lo = t * CHUNK;
    int hi = lo + CHUNK; if (hi > N_NODES) hi = N_NODES;
    int s = 0;
    for (int i = lo; i < hi; ++i) s += deg[i];
    sums[t] = s;
    __syncthreads();
    for (int d = 1; d < 1024; d <<= 1) {
        int other = (t >= d) ? sums[t - d] : 0;
        __syncthreads();
        sums[t] += other;
        __syncthreads();
    }
    int run = sums[t] - s;  // exclusive prefix of this chunk
    for (int i = lo; i < hi; ++i) {
        off[i] = run;
        cursor[i] = run;
        run += deg[i];
        dinv[i] = rsqrtf((float)deg[i] + 1.0f);  // +1 self loop
    }
}

// ---------------- bucket fill: srow sorted by col ----------------
__global__ __launch_bounds__(256) void k_fill(const int* __restrict__ row, const int* __restrict__ col,
                                              int* __restrict__ cursor, int* __restrict__ srow) {
    int i = blockIdx.x * 256 + threadIdx.x;
    int stride = gridDim.x * 256;
    for (int e = i; e < N_EDGES; e += stride) {
        int c = col[e];
        int pos = atomicAdd(&cursor[c], 1);
        srow[pos] = row[e];
    }
}

// ---------------- tiled dense GEMM: O[N][C] = X[N][K] @ W[C][K]^T, fp16 out ----------------
// W staged once per block (padded +4 floats per row -> conflict-free b128 reads).
// Block owns ROWS_PB rows, chunks of 32 staged via coalesced float4.
template<int K, int C, int ROWS_PB>
__global__ __launch_bounds__(256) void k_gemm(const float* __restrict__ X, const float* __restrict__ W,
                                              __half* __restrict__ O) {
    constexpr int PK = K + 4;
    __shared__ float ws[C * PK];
    __shared__ float xs[32 * PK];
    int t = threadIdx.x;
    for (int i4 = t; i4 < C * K / 4; i4 += 256) {
        int j = i4 / (K / 4);
        int k4 = i4 % (K / 4);
        float4 v = ((const float4*)W)[i4];
        *(float4*)&ws[j * PK + k4 * 4] = v;
    }
    int j = t & 63;
    int r0 = (t >> 6) * 8;   // 8 rows per thread, 4 thread-groups cover 32
    int rowbase = blockIdx.x * ROWS_PB;
    for (int chunk = 0; chunk < ROWS_PB; chunk += 32) {
        int cb = rowbase + chunk;
        __syncthreads();   // protect xs (and ws on first iter)
        for (int i4 = t; i4 < 32 * K / 4; i4 += 256) {
            int r = i4 / (K / 4);
            int k4 = i4 % (K / 4);
            int rr = cb + r;
            float4 v = make_float4(0.f, 0.f, 0.f, 0.f);
            if (rr < N_NODES) v = ((const float4*)X)[(size_t)rr * (K / 4) + k4];
            *(float4*)&xs[r * PK + k4 * 4] = v;
        }
        __syncthreads();
        if (j < C) {
            float acc[8] = {0.f, 0.f, 0.f, 0.f, 0.f, 0.f, 0.f, 0.f};
            for (int k4 = 0; k4 < K / 4; ++k4) {
                float4 wv = *(const float4*)&ws[j * PK + k4 * 4];
#pragma unroll
                for (int r = 0; r < 8; ++r) {
                    float4 xv = *(const float4*)&xs[(r0 + r) * PK + k4 * 4];
                    acc[r] += xv.x * wv.x + xv.y * wv.y + xv.z * wv.z + xv.w * wv.w;
                }
            }
#pragma unroll
            for (int r = 0; r < 8; ++r) {
                int rr = cb + r0 + r;
                if (rr < N_NODES) O[(size_t)rr * C + j] = __float2half(acc[r]);
            }
        }
    }
}

// ---------------- layer-1 aggregation (fp16 gather), fused self-loop+bias+relu ----------------
__global__ __launch_bounds__(256) void k_agg1(const int* __restrict__ off, const int* __restrict__ deg,
                                              const int* __restrict__ srow, const float* __restrict__ dinv,
                                              const __half* __restrict__ h1, const float* __restrict__ b1,
                                              float* __restrict__ o1) {
    int node = (blockIdx.x * 256 + threadIdx.x) >> 6;
    int lane = threadIdx.x & 63;
    if (node >= N_NODES) return;
    int start = off[node];
    int end = start + deg[node];
    float acc = 0.f;
#pragma unroll 4
    for (int j = start; j < end; ++j) {
        int r = srow[j];
        acc += dinv[r] * __half2float(h1[(size_t)r * HID + lane]);
    }
    float dc = dinv[node];
    float v = dc * acc + dc * dc * __half2float(h1[(size_t)node * HID + lane]) + b1[lane];
    o1[(size_t)node * HID + lane] = v > 0.f ? v : 0.f;
}

// ---------------- layer-2 aggregation + softmax/logsoftmax/argmax, fused ----------------
__global__ __launch_bounds__(256) void k_agg2(const int* __restrict__ off, const int* __restrict__ deg,
                                              const int* __restrict__ srow, const float* __restrict__ dinv,
                                              const __half* __restrict__ h2, const float* __restrict__ b2,
                                              const int* __restrict__ y,
                                              float* __restrict__ out, unsigned short* __restrict__ ps) {
    int node = (blockIdx.x * 256 + threadIdx.x) >> 6;
    int lane = threadIdx.x & 63;
    if (node >= N_NODES) return;
    int start = off[node];
    int end = start + deg[node];
    bool act = lane < N_CLASS;
    float acc = 0.f;
#pragma unroll 4
    for (int j = start; j < end; ++j) {
        int r = srow[j];
        if (act) acc += dinv[r] * __half2float(h2[(size_t)r * N_CLASS + lane]);
    }
    float dc = dinv[node];
    float v = -1e30f;
    if (act) {
        v = dc * acc + dc * dc * __half2float(h2[(size_t)node * N_CLASS + lane]) + b2[lane];
    }
    // wave-wide max
    float m = v;
#pragma unroll
    for (int k = 1; k < 64; k <<= 1) {
        float o = __shfl_xor(m, k);
        m = o > m ? o : m;
    }
    // wave-wide sum of exp
    float sv = act ? expf(v - m) : 0.f;
    float s = sv;
#pragma unroll
    for (int k = 1; k < 64; k <<= 1) s += __shfl_xor(s, k);
    float ls = logf(s);
    // argmax (first occurrence)
    float av = v;
    int ai = act ? lane : 64;
#pragma unroll
    for (int k = 1; k < 64; k <<= 1) {
        float ov = __shfl_xor(av, k);
        int oi = __shfl_xor(ai, k);
        if (ov > av || (ov == av && oi < ai)) { av = ov; ai = oi; }
    }
    if (act) {
        float lp = (v - m) - ls;
        float* logp = out;
        float* p = out + (size_t)N_NODES * N_CLASS;
        logp[(size_t)node * N_CLASS + lane] = lp;
        p[(size_t)node * N_CLASS + lane] = expf(lp);
    }
    if (lane == 0) ps[node] = (unsigned short)((y[node] << 8) | ai);
}

// ---------------- ratio over original edges (packed y|pred gather) ----------------
__global__ __launch_bounds__(256) void k_ratio(const int* __restrict__ row, const int* __restrict__ col,
                                               const unsigned short* __restrict__ ps,
                                               unsigned int* __restrict__ cnt) {
    int i = blockIdx.x * 256 + threadIdx.x;
    int stride = gridDim.x * 256;
    unsigned int local = 0;
    for (int e = i; e < N_EDGES; e += stride) {
        unsigned int a = ps[row[e]];
        unsigned int b = ps[col[e]];
        bool sp = (a & 0xffu) == (b & 0xffu);
        bool sy = (a >> 8) == (b >> 8);
        local += (sp == sy) ? 1u : 0u;
    }
    if (local) atomicAdd(cnt, local);
}

__global__ void k_fin(const unsigned int* __restrict__ cnt, float* __restrict__ out) {
    out[0] = (float)(*cnt) / (float)N_EDGES;
}

extern "C" void kernel_launch(void* const* d_in, const int* in_sizes, int n_in,
                              void* d_out, int out_size, void* d_ws, size_t ws_size,
                              hipStream_t stream) {
    const float* x  = (const float*)d_in[0];
    const int*   ei = (const int*)d_in[1];
    const int*   y  = (const int*)d_in[2];
    const float* W1 = (const float*)d_in[3];
    const float* b1 = (const float*)d_in[4];
    const float* W2 = (const float*)d_in[5];
    const float* b2 = (const float*)d_in[6];

    const int* row = ei;             // edge_index[0]
    const int* col = ei + N_EDGES;   // edge_index[1]

    float* ws = (float*)d_ws;
    // workspace layout (float-sized slots; h1/h2 now fp16 so slots oversized)
    __half* h1    = (__half*)ws;                 // N*64 halves (12.8 MB)
    float* o1     = ws + 6400000;                // N*64 fp32
    __half* h2    = (__half*)(ws + 12800000);    // N*40 halves (8 MB)
    float* dinv   = ws + 16800000;               // N
    int*   deg    = (int*)(ws + 16900000);       // N
    int*   off    = (int*)(ws + 17000000);       // N
    int*   cursor = (int*)(ws + 17100000);       // N
    int*   srow   = (int*)(ws + 17200000);       // E
    unsigned short* ps = (unsigned short*)(ws + 20400000);  // N (packed y<<8|pred)
    unsigned int* cnt = (unsigned int*)(ws + 20500000);

    float* out = (float*)d_out;   // logp [N*40], p [N*40], ratio [1]

    hipMemsetAsync(deg, 0, (size_t)N_NODES * 4, stream);
    hipMemsetAsync(cnt, 0, 4, stream);

    const int GEMM_GRID = (N_NODES + 127) / 128;   // 782 blocks, 128 rows each

    k_deg<<<2048, 256, 0, stream>>>(col, deg);
    k_scan<<<1, 1024, 0, stream>>>(deg, off, cursor, dinv);
    k_fill<<<2048, 256, 0, stream>>>(row, col, cursor, srow);
    k_gemm<F_IN, HID, 128><<<GEMM_GRID, 256, 0, stream>>>(x, W1, h1);
    k_agg1<<<(N_NODES * 64 + 255) / 256, 256, 0, stream>>>(off, deg, srow, dinv, h1, b1, o1);
    k_gemm<HID, N_CLASS, 128><<<GEMM_GRID, 256, 0, stream>>>(o1, W2, h2);
    k_agg2<<<(N_NODES * 64 + 255) / 256, 256, 0, stream>>>(off, deg, srow, dinv, h2, b2, y, out, ps);
    k_ratio<<<2048, 256, 0, stream>>>(row, col, ps, cnt);
    k_fin<<<1, 1, 0, stream>>>(cnt, out + (size_t)2 * N_NODES * N_CLASS);
}

// Round 10
// 677.608 us; speedup vs baseline: 2.8655x; 1.9759x over previous
//
#include <hip/hip_runtime.h>
#include <hip/hip_fp16.h>

#define N_NODES 100000
#define N_EDGES 3200000
#define F_IN 128
#define HID 64
#define N_CLASS 40

#define NBUCK 196          // ceil(100000/512)
#define BSHIFT 9           // bucket = col >> 9, local = col & 511
#define NBLK_A 512
#define CHUNK_A ((N_EDGES + NBLK_A - 1) / NBLK_A)   // 6250

// ---------------- Phase A1: per-block bucket histogram ----------------
__global__ __launch_bounds__(256) void k_A1(const int* __restrict__ col, int* __restrict__ ghist) {
    __shared__ int hist[256];
    int t = threadIdx.x;
    hist[t] = 0;
    __syncthreads();
    int e0 = blockIdx.x * CHUNK_A;
    int e1 = e0 + CHUNK_A; if (e1 > N_EDGES) e1 = N_EDGES;
    for (int e = e0 + t; e < e1; e += 256) {
        atomicAdd(&hist[col[e] >> BSHIFT], 1);
    }
    __syncthreads();
    ghist[blockIdx.x * 256 + t] = hist[t];
}

// ---------------- Phase A2: scan -> per-block bucket offsets ----------------
__global__ __launch_bounds__(256) void k_A2(const int* __restrict__ ghist, int* __restrict__ goff,
                                            int* __restrict__ bbase, int* __restrict__ bend) {
    __shared__ int sums[256];
    int b = threadIdx.x;
    int tot = 0;
    for (int k = 0; k < NBLK_A; ++k) tot += ghist[k * 256 + b];
    sums[b] = tot;
    __syncthreads();
    for (int d = 1; d < 256; d <<= 1) {
        int o = (b >= d) ? sums[b - d] : 0;
        __syncthreads();
        sums[b] += o;
        __syncthreads();
    }
    int base = sums[b] - tot;   // exclusive
    bbase[b] = base;
    bend[b] = base + tot;
    int run = base;
    for (int k = 0; k < NBLK_A; ++k) {
        goff[k * 256 + b] = run;
        run += ghist[k * 256 + b];
    }
}

// ---------------- Phase A3: coalesced-reserved bucket scatter (packed key) ----------------
__global__ __launch_bounds__(256) void k_A3(const int* __restrict__ row, const int* __restrict__ col,
                                            const int* __restrict__ goff, unsigned int* __restrict__ epair) {
    __shared__ int cur[256];
    int t = threadIdx.x;
    cur[t] = goff[blockIdx.x * 256 + t];
    __syncthreads();
    int e0 = blockIdx.x * CHUNK_A;
    int e1 = e0 + CHUNK_A; if (e1 > N_EDGES) e1 = N_EDGES;
    for (int e = e0 + t; e < e1; e += 256) {
        int c = col[e];
        int pos = atomicAdd(&cur[c >> BSHIFT], 1);
        epair[pos] = ((unsigned int)(c & 511) << 17) | (unsigned int)row[e];
    }
}

// ---------------- Phase B: per-bucket CSR build + srow scatter (L2-local) ----------------
__global__ __launch_bounds__(256) void k_B(const unsigned int* __restrict__ epair,
                                           const int* __restrict__ bbase, const int* __restrict__ bend,
                                           int* __restrict__ off, int* __restrict__ deg,
                                           float* __restrict__ dinv, int* __restrict__ srow) {
    __shared__ int h[512];
    __shared__ int psc[256];
    int t = threadIdx.x;
    int b = blockIdx.x;
    int n0 = b << BSHIFT;
    int e0 = bbase[b], e1 = bend[b];
    h[t] = 0; h[t + 256] = 0;
    __syncthreads();
    for (int e = e0 + t; e < e1; e += 256) {
        atomicAdd(&h[epair[e] >> 17], 1);
    }
    __syncthreads();
    int a0 = h[2 * t], a1 = h[2 * t + 1];
    psc[t] = a0 + a1;
    __syncthreads();
    for (int d = 1; d < 256; d <<= 1) {
        int o = (t >= d) ? psc[t - d] : 0;
        __syncthreads();
        psc[t] += o;
        __syncthreads();
    }
    int base0 = e0 + psc[t] - (a0 + a1);
    h[2 * t] = base0;
    h[2 * t + 1] = base0 + a0;
    int n = n0 + 2 * t;
    if (n < N_NODES) {
        off[n] = base0; deg[n] = a0; dinv[n] = rsqrtf((float)a0 + 1.0f);
    }
    if (n + 1 < N_NODES) {
        off[n + 1] = base0 + a0; deg[n + 1] = a1; dinv[n + 1] = rsqrtf((float)a1 + 1.0f);
    }
    __syncthreads();
    for (int e = e0 + t; e < e1; e += 256) {
        unsigned int k = epair[e];
        int c = k >> 17;
        int pos = atomicAdd(&h[c], 1);
        srow[pos] = (int)(k & 0x1FFFFu);
    }
}

// ---------------- tiled dense GEMM: O[N][C] = scale[n] * (X @ W^T), fp16 out ----------------
template<int K, int C, int ROWS_PB>
__global__ __launch_bounds__(256) void k_gemm(const float* __restrict__ X, const float* __restrict__ W,
                                              const float* __restrict__ scale, __half* __restrict__ O) {
    constexpr int PK = K + 4;
    __shared__ float ws[C * PK];
    __shared__ float xs[32 * PK];
    int t = threadIdx.x;
    for (int i4 = t; i4 < C * K / 4; i4 += 256) {
        int j = i4 / (K / 4);
        int k4 = i4 % (K / 4);
        float4 v = ((const float4*)W)[i4];
        *(float4*)&ws[j * PK + k4 * 4] = v;
    }
    int j = t & 63;
    int r0 = (t >> 6) * 8;
    int rowbase = blockIdx.x * ROWS_PB;
    for (int chunk = 0; chunk < ROWS_PB; chunk += 32) {
        int cb = rowbase + chunk;
        __syncthreads();
        for (int i4 = t; i4 < 32 * K / 4; i4 += 256) {
            int r = i4 / (K / 4);
            int k4 = i4 % (K / 4);
            int rr = cb + r;
            float4 v = make_float4(0.f, 0.f, 0.f, 0.f);
            if (rr < N_NODES) v = ((const float4*)X)[(size_t)rr * (K / 4) + k4];
            *(float4*)&xs[r * PK + k4 * 4] = v;
        }
        __syncthreads();
        if (j < C) {
            float acc[8] = {0.f, 0.f, 0.f, 0.f, 0.f, 0.f, 0.f, 0.f};
            for (int k4 = 0; k4 < K / 4; ++k4) {
                float4 wv = *(const float4*)&ws[j * PK + k4 * 4];
#pragma unroll
                for (int r = 0; r < 8; ++r) {
                    float4 xv = *(const float4*)&xs[(r0 + r) * PK + k4 * 4];
                    acc[r] += xv.x * wv.x + xv.y * wv.y + xv.z * wv.z + xv.w * wv.w;
                }
            }
#pragma unroll
            for (int r = 0; r < 8; ++r) {
                int rr = cb + r0 + r;
                if (rr < N_NODES) O[(size_t)rr * C + j] = __float2half(acc[r] * scale[rr]);
            }
        }
    }
}

// ---------------- layer-1 aggregation: single gather/edge, 8-wide MLP ----------------
__global__ __launch_bounds__(256) void k_agg1(const int* __restrict__ off, const int* __restrict__ deg,
                                              const int* __restrict__ srow, const float* __restrict__ dinv,
                                              const __half* __restrict__ h1s, const float* __restrict__ b1,
                                              float* __restrict__ o1) {
    int node = (blockIdx.x * 256 + threadIdx.x) >> 6;
    int lane = threadIdx.x & 63;
    if (node >= N_NODES) return;
    int start = off[node];
    int end = start + deg[node];
    float acc = 0.f;
    int j = start;
    for (; j + 8 <= end; j += 8) {
        int rs[8];
#pragma unroll
        for (int k = 0; k < 8; ++k) rs[k] = srow[j + k];
        float vs[8];
#pragma unroll
        for (int k = 0; k < 8; ++k) vs[k] = __half2float(h1s[(size_t)rs[k] * HID + lane]);
#pragma unroll
        for (int k = 0; k < 8; ++k) acc += vs[k];
    }
    for (; j < end; ++j) acc += __half2float(h1s[(size_t)srow[j] * HID + lane]);
    float dc = dinv[node];
    float v = dc * (acc + __half2float(h1s[(size_t)node * HID + lane])) + b1[lane];
    o1[(size_t)node * HID + lane] = v > 0.f ? v : 0.f;
}

// ---------------- layer-2 aggregation + softmax/logsoftmax/argmax ----------------
__global__ __launch_bounds__(256) void k_agg2(const int* __restrict__ off, const int* __restrict__ deg,
                                              const int* __restrict__ srow, const float* __restrict__ dinv,
                                              const __half* __restrict__ h2s, const float* __restrict__ b2,
                                              const int* __restrict__ y,
                                              float* __restrict__ out, unsigned short* __restrict__ ps) {
    int node = (blockIdx.x * 256 + threadIdx.x) >> 6;
    int lane = threadIdx.x & 63;
    if (node >= N_NODES) return;
    int start = off[node];
    int end = start + deg[node];
    bool act = lane < N_CLASS;
    float acc = 0.f;
    int j = start;
    for (; j + 8 <= end; j += 8) {
        int rs[8];
#pragma unroll
        for (int k = 0; k < 8; ++k) rs[k] = srow[j + k];
        float vs[8];
#pragma unroll
        for (int k = 0; k < 8; ++k) vs[k] = act ? __half2float(h2s[(size_t)rs[k] * N_CLASS + lane]) : 0.f;
#pragma unroll
        for (int k = 0; k < 8; ++k) acc += vs[k];
    }
    for (; j < end; ++j) {
        int r = srow[j];
        if (act) acc += __half2float(h2s[(size_t)r * N_CLASS + lane]);
    }
    float dc = dinv[node];
    float v = -1e30f;
    if (act) v = dc * (acc + __half2float(h2s[(size_t)node * N_CLASS + lane])) + b2[lane];
    float m = v;
#pragma unroll
    for (int k = 1; k < 64; k <<= 1) {
        float o = __shfl_xor(m, k);
        m = o > m ? o : m;
    }
    float sv = act ? expf(v - m) : 0.f;
    float s = sv;
#pragma unroll
    for (int k = 1; k < 64; k <<= 1) s += __shfl_xor(s, k);
    float ls = logf(s);
    float av = v;
    int ai = act ? lane : 64;
#pragma unroll
    for (int k = 1; k < 64; k <<= 1) {
        float ov = __shfl_xor(av, k);
        int oi = __shfl_xor(ai, k);
        if (ov > av || (ov == av && oi < ai)) { av = ov; ai = oi; }
    }
    if (act) {
        float lp = (v - m) - ls;
        float* logp = out;
        float* p = out + (size_t)N_NODES * N_CLASS;
        logp[(size_t)node * N_CLASS + lane] = lp;
        p[(size_t)node * N_CLASS + lane] = expf(lp);
    }
    if (lane == 0) ps[node] = (unsigned short)((y[node] << 8) | ai);
}

// ---------------- ratio over original edges (packed y|pred gather, int4 edges) ----------------
__global__ __launch_bounds__(256) void k_ratio(const int* __restrict__ row, const int* __restrict__ col,
                                               const unsigned short* __restrict__ ps,
                                               unsigned int* __restrict__ cnt) {
    int i = blockIdx.x * 256 + threadIdx.x;
    int stride = gridDim.x * 256;
    unsigned int local = 0;
    for (int e4 = i; e4 < N_EDGES / 4; e4 += stride) {
        int4 r4 = ((const int4*)row)[e4];
        int4 c4 = ((const int4*)col)[e4];
        unsigned int a, b;
        a = ps[r4.x]; b = ps[c4.x];
        local += (((a & 0xffu) == (b & 0xffu)) == ((a >> 8) == (b >> 8))) ? 1u : 0u;
        a = ps[r4.y]; b = ps[c4.y];
        local += (((a & 0xffu) == (b & 0xffu)) == ((a >> 8) == (b >> 8))) ? 1u : 0u;
        a = ps[r4.z]; b = ps[c4.z];
        local += (((a & 0xffu) == (b & 0xffu)) == ((a >> 8) == (b >> 8))) ? 1u : 0u;
        a = ps[r4.w]; b = ps[c4.w];
        local += (((a & 0xffu) == (b & 0xffu)) == ((a >> 8) == (b >> 8))) ? 1u : 0u;
    }
    if (local) atomicAdd(cnt, local);
}

__global__ void k_fin(const unsigned int* __restrict__ cnt, float* __restrict__ out) {
    out[0] = (float)(*cnt) / (float)N_EDGES;
}

extern "C" void kernel_launch(void* const* d_in, const int* in_sizes, int n_in,
                              void* d_out, int out_size, void* d_ws, size_t ws_size,
                              hipStream_t stream) {
    const float* x  = (const float*)d_in[0];
    const int*   ei = (const int*)d_in[1];
    const int*   y  = (const int*)d_in[2];
    const float* W1 = (const float*)d_in[3];
    const float* b1 = (const float*)d_in[4];
    const float* W2 = (const float*)d_in[5];
    const float* b2 = (const float*)d_in[6];

    const int* row = ei;             // edge_index[0]
    const int* col = ei + N_EDGES;   // edge_index[1]

    float* ws = (float*)d_ws;
    // workspace layout (4B units)
    __half* h1s   = (__half*)ws;                    // N*64 fp16  -> 3.2M units
    __half* h2s   = (__half*)(ws + 3200000);        // N*40 fp16  -> 2.0M units
    float* dinv   = ws + 5200000;                   // N
    int*   deg    = (int*)(ws + 5300000);           // N
    int*   off    = (int*)(ws + 5400000);           // N
    int*   srow   = (int*)(ws + 5500000);           // E (3.2M)
    int*   ghist  = (int*)(ws + 8700000);           // 512*256
    int*   goff   = (int*)(ws + 8850000);           // 512*256
    int*   bbase  = (int*)(ws + 9000000);           // 256
    int*   bend   = (int*)(ws + 9001000);           // 256
    unsigned short* ps = (unsigned short*)(ws + 9100000);   // N ushort
    unsigned int* cnt  = (unsigned int*)(ws + 9200000);
    unsigned int* epair = (unsigned int*)(ws + 9300000);    // E uint32 (3.2M)
    float* o1     = ws + 9300000;                   // N*64 fp32 (6.4M) — reuses epair after k_B

    float* out = (float*)d_out;   // logp [N*40], p [N*40], ratio [1]

    hipMemsetAsync(cnt, 0, 4, stream);

    const int GEMM_GRID = (N_NODES + 127) / 128;

    k_A1<<<NBLK_A, 256, 0, stream>>>(col, ghist);
    k_A2<<<1, 256, 0, stream>>>(ghist, goff, bbase, bend);
    k_A3<<<NBLK_A, 256, 0, stream>>>(row, col, goff, epair);
    k_B<<<NBUCK, 256, 0, stream>>>(epair, bbase, bend, off, deg, dinv, srow);
    k_gemm<F_IN, HID, 128><<<GEMM_GRID, 256, 0, stream>>>(x, W1, dinv, h1s);
    k_agg1<<<(N_NODES * 64 + 255) / 256, 256, 0, stream>>>(off, deg, srow, dinv, h1s, b1, o1);
    k_gemm<HID, N_CLASS, 128><<<GEMM_GRID, 256, 0, stream>>>(o1, W2, dinv, h2s);
    k_agg2<<<(N_NODES * 64 + 255) / 256, 256, 0, stream>>>(off, deg, srow, dinv, h2s, b2, y, out, ps);
    k_ratio<<<2048, 256, 0, stream>>>(row, col, ps, cnt);
    k_fin<<<1, 1, 0, stream>>>(cnt, out + (size_t)2 * N_NODES * N_CLASS);
}

// Round 11
// 576.426 us; speedup vs baseline: 3.3685x; 1.1755x over previous
//
#include <hip/hip_runtime.h>
#include <hip/hip_fp16.h>

#define N_NODES 100000
#define N_EDGES 3200000
#define F_IN 128
#define HID 64
#define N_CLASS 40
#define H2S 64             // padded stride for h2 rows (one 128B line)

#define NBUCK 196          // ceil(100000/512)
#define BSHIFT 9           // bucket = col >> 9, local = col & 511
#define NBLK_A 512
#define CHUNK_A ((N_EDGES + NBLK_A - 1) / NBLK_A)   // 6250

// ---------------- Phase A1: per-block bucket histogram ----------------
__global__ __launch_bounds__(256) void k_A1(const int* __restrict__ col, int* __restrict__ ghist) {
    __shared__ int hist[256];
    int t = threadIdx.x;
    hist[t] = 0;
    __syncthreads();
    int e0 = blockIdx.x * CHUNK_A;
    int e1 = e0 + CHUNK_A; if (e1 > N_EDGES) e1 = N_EDGES;
    for (int e = e0 + t; e < e1; e += 256) {
        atomicAdd(&hist[col[e] >> BSHIFT], 1);
    }
    __syncthreads();
    ghist[blockIdx.x * 256 + t] = hist[t];
}

// ---------------- Phase A2: scan -> per-block bucket offsets ----------------
__global__ __launch_bounds__(256) void k_A2(const int* __restrict__ ghist, int* __restrict__ goff,
                                            int* __restrict__ bbase, int* __restrict__ bend) {
    __shared__ int sums[256];
    int b = threadIdx.x;
    int tot = 0;
    for (int k = 0; k < NBLK_A; ++k) tot += ghist[k * 256 + b];
    sums[b] = tot;
    __syncthreads();
    for (int d = 1; d < 256; d <<= 1) {
        int o = (b >= d) ? sums[b - d] : 0;
        __syncthreads();
        sums[b] += o;
        __syncthreads();
    }
    int base = sums[b] - tot;   // exclusive
    bbase[b] = base;
    bend[b] = base + tot;
    int run = base;
    for (int k = 0; k < NBLK_A; ++k) {
        goff[k * 256 + b] = run;
        run += ghist[k * 256 + b];
    }
}

// ---------------- Phase A3: coalesced-reserved bucket scatter (packed key) ----------------
__global__ __launch_bounds__(256) void k_A3(const int* __restrict__ row, const int* __restrict__ col,
                                            const int* __restrict__ goff, unsigned int* __restrict__ epair) {
    __shared__ int cur[256];
    int t = threadIdx.x;
    cur[t] = goff[blockIdx.x * 256 + t];
    __syncthreads();
    int e0 = blockIdx.x * CHUNK_A;
    int e1 = e0 + CHUNK_A; if (e1 > N_EDGES) e1 = N_EDGES;
    for (int e = e0 + t; e < e1; e += 256) {
        int c = col[e];
        int pos = atomicAdd(&cur[c >> BSHIFT], 1);
        epair[pos] = ((unsigned int)(c & 511) << 17) | (unsigned int)row[e];
    }
}

// ---------------- Phase B: per-bucket CSR build + srow scatter (L2-local) ----------------
__global__ __launch_bounds__(256) void k_B(const unsigned int* __restrict__ epair,
                                           const int* __restrict__ bbase, const int* __restrict__ bend,
                                           int* __restrict__ off, int* __restrict__ deg,
                                           float* __restrict__ dinv, int* __restrict__ srow) {
    __shared__ int h[512];
    __shared__ int psc[256];
    int t = threadIdx.x;
    int b = blockIdx.x;
    int n0 = b << BSHIFT;
    int e0 = bbase[b], e1 = bend[b];
    h[t] = 0; h[t + 256] = 0;
    __syncthreads();
    for (int e = e0 + t; e < e1; e += 256) {
        atomicAdd(&h[epair[e] >> 17], 1);
    }
    __syncthreads();
    int a0 = h[2 * t], a1 = h[2 * t + 1];
    psc[t] = a0 + a1;
    __syncthreads();
    for (int d = 1; d < 256; d <<= 1) {
        int o = (t >= d) ? psc[t - d] : 0;
        __syncthreads();
        psc[t] += o;
        __syncthreads();
    }
    int base0 = e0 + psc[t] - (a0 + a1);
    h[2 * t] = base0;
    h[2 * t + 1] = base0 + a0;
    int n = n0 + 2 * t;
    if (n < N_NODES) {
        off[n] = base0; deg[n] = a0; dinv[n] = rsqrtf((float)a0 + 1.0f);
    }
    if (n + 1 < N_NODES) {
        off[n + 1] = base0 + a0; deg[n + 1] = a1; dinv[n + 1] = rsqrtf((float)a1 + 1.0f);
    }
    __syncthreads();
    for (int e = e0 + t; e < e1; e += 256) {
        unsigned int k = epair[e];
        int c = k >> 17;
        int pos = atomicAdd(&h[c], 1);
        srow[pos] = (int)(k & 0x1FFFFu);
    }
}

// ---------------- tiled dense GEMM: O[N][OS] = scale[n] * (X @ W^T), fp16 out ----------------
template<int K, int C, int OS, int ROWS_PB>
__global__ __launch_bounds__(256) void k_gemm(const float* __restrict__ X, const float* __restrict__ W,
                                              const float* __restrict__ scale, __half* __restrict__ O) {
    constexpr int PK = K + 4;
    __shared__ float ws[C * PK];
    __shared__ float xs[32 * PK];
    int t = threadIdx.x;
    for (int i4 = t; i4 < C * K / 4; i4 += 256) {
        int j = i4 / (K / 4);
        int k4 = i4 % (K / 4);
        float4 v = ((const float4*)W)[i4];
        *(float4*)&ws[j * PK + k4 * 4] = v;
    }
    int j = t & 63;
    int r0 = (t >> 6) * 8;
    int rowbase = blockIdx.x * ROWS_PB;
    for (int chunk = 0; chunk < ROWS_PB; chunk += 32) {
        int cb = rowbase + chunk;
        __syncthreads();
        for (int i4 = t; i4 < 32 * K / 4; i4 += 256) {
            int r = i4 / (K / 4);
            int k4 = i4 % (K / 4);
            int rr = cb + r;
            float4 v = make_float4(0.f, 0.f, 0.f, 0.f);
            if (rr < N_NODES) v = ((const float4*)X)[(size_t)rr * (K / 4) + k4];
            *(float4*)&xs[r * PK + k4 * 4] = v;
        }
        __syncthreads();
        if (j < C) {
            float acc[8] = {0.f, 0.f, 0.f, 0.f, 0.f, 0.f, 0.f, 0.f};
            for (int k4 = 0; k4 < K / 4; ++k4) {
                float4 wv = *(const float4*)&ws[j * PK + k4 * 4];
#pragma unroll
                for (int r = 0; r < 8; ++r) {
                    float4 xv = *(const float4*)&xs[(r0 + r) * PK + k4 * 4];
                    acc[r] += xv.x * wv.x + xv.y * wv.y + xv.z * wv.z + xv.w * wv.w;
                }
            }
#pragma unroll
            for (int r = 0; r < 8; ++r) {
                int rr = cb + r0 + r;
                if (rr < N_NODES) O[(size_t)rr * OS + j] = __float2half(acc[r] * scale[rr]);
            }
        }
    }
}

// ---------------- layer-1 aggregation: forced 8-deep gather pipeline ----------------
__global__ __launch_bounds__(256) void k_agg1(const int* __restrict__ off, const int* __restrict__ deg,
                                              const int* __restrict__ srow, const float* __restrict__ dinv,
                                              const __half* __restrict__ h1s, const float* __restrict__ b1,
                                              float* __restrict__ o1) {
    int node = (blockIdx.x * 256 + threadIdx.x) >> 6;
    int lane = threadIdx.x & 63;
    if (node >= N_NODES) return;
    int start = off[node];
    int end = start + deg[node];
    float acc = 0.f;
    int j = start;
    int nb = (end - start) >> 3;
    if (nb > 0) {
        int idx[8];
#pragma unroll
        for (int k = 0; k < 8; ++k) idx[k] = srow[j + k];
        for (int b = 1; b <= nb; ++b) {
            __half raw[8];
#pragma unroll
            for (int k = 0; k < 8; ++k) raw[k] = h1s[(size_t)idx[k] * HID + lane];   // 8 independent gathers
            int jn = j + 8;
            if (b < nb) {
#pragma unroll
                for (int k = 0; k < 8; ++k) idx[k] = srow[jn + k];                   // prefetch next indices
            }
            __builtin_amdgcn_sched_barrier(0);   // loads may not sink below this point
#pragma unroll
            for (int k = 0; k < 8; ++k) acc += __half2float(raw[k]);
            j = jn;
        }
    }
    for (; j < end; ++j) acc += __half2float(h1s[(size_t)srow[j] * HID + lane]);
    float dc = dinv[node];
    float v = dc * (acc + __half2float(h1s[(size_t)node * HID + lane])) + b1[lane];
    o1[(size_t)node * HID + lane] = v > 0.f ? v : 0.f;
}

// ---------------- layer-2 aggregation + softmax/logsoftmax/argmax ----------------
__global__ __launch_bounds__(256) void k_agg2(const int* __restrict__ off, const int* __restrict__ deg,
                                              const int* __restrict__ srow, const float* __restrict__ dinv,
                                              const __half* __restrict__ h2s, const float* __restrict__ b2,
                                              const int* __restrict__ y,
                                              float* __restrict__ out, unsigned short* __restrict__ ps) {
    int node = (blockIdx.x * 256 + threadIdx.x) >> 6;
    int lane = threadIdx.x & 63;
    if (node >= N_NODES) return;
    int start = off[node];
    int end = start + deg[node];
    int cl = lane < N_CLASS ? lane : N_CLASS - 1;   // unconditional loads, lanes 40-63 mirror lane 39
    bool act = lane < N_CLASS;
    float acc = 0.f;
    int j = start;
    int nb = (end - start) >> 3;
    if (nb > 0) {
        int idx[8];
#pragma unroll
        for (int k = 0; k < 8; ++k) idx[k] = srow[j + k];
        for (int b = 1; b <= nb; ++b) {
            __half raw[8];
#pragma unroll
            for (int k = 0; k < 8; ++k) raw[k] = h2s[(size_t)idx[k] * H2S + cl];
            int jn = j + 8;
            if (b < nb) {
#pragma unroll
                for (int k = 0; k < 8; ++k) idx[k] = srow[jn + k];
            }
            __builtin_amdgcn_sched_barrier(0);
#pragma unroll
            for (int k = 0; k < 8; ++k) acc += __half2float(raw[k]);
            j = jn;
        }
    }
    for (; j < end; ++j) acc += __half2float(h2s[(size_t)srow[j] * H2S + cl]);
    float dc = dinv[node];
    float v = -1e30f;
    if (act) v = dc * (acc + __half2float(h2s[(size_t)node * H2S + cl])) + b2[lane];
    float m = v;
#pragma unroll
    for (int k = 1; k < 64; k <<= 1) {
        float o = __shfl_xor(m, k);
        m = o > m ? o : m;
    }
    float sv = act ? expf(v - m) : 0.f;
    float s = sv;
#pragma unroll
    for (int k = 1; k < 64; k <<= 1) s += __shfl_xor(s, k);
    float ls = logf(s);
    float av = v;
    int ai = act ? lane : 64;
#pragma unroll
    for (int k = 1; k < 64; k <<= 1) {
        float ov = __shfl_xor(av, k);
        int oi = __shfl_xor(ai, k);
        if (ov > av || (ov == av && oi < ai)) { av = ov; ai = oi; }
    }
    if (act) {
        float lp = (v - m) - ls;
        float* logp = out;
        float* p = out + (size_t)N_NODES * N_CLASS;
        logp[(size_t)node * N_CLASS + lane] = lp;
        p[(size_t)node * N_CLASS + lane] = expf(lp);
    }
    if (lane == 0) ps[node] = (unsigned short)((y[node] << 8) | ai);
}

// ---------------- ratio over original edges (packed y|pred gather, int4 edges) ----------------
__global__ __launch_bounds__(256) void k_ratio(const int* __restrict__ row, const int* __restrict__ col,
                                               const unsigned short* __restrict__ ps,
                                               unsigned int* __restrict__ cnt) {
    int i = blockIdx.x * 256 + threadIdx.x;
    int stride = gridDim.x * 256;
    unsigned int local = 0;
    for (int e4 = i; e4 < N_EDGES / 4; e4 += stride) {
        int4 r4 = ((const int4*)row)[e4];
        int4 c4 = ((const int4*)col)[e4];
        unsigned int a, b;
        a = ps[r4.x]; b = ps[c4.x];
        local += (((a & 0xffu) == (b & 0xffu)) == ((a >> 8) == (b >> 8))) ? 1u : 0u;
        a = ps[r4.y]; b = ps[c4.y];
        local += (((a & 0xffu) == (b & 0xffu)) == ((a >> 8) == (b >> 8))) ? 1u : 0u;
        a = ps[r4.z]; b = ps[c4.z];
        local += (((a & 0xffu) == (b & 0xffu)) == ((a >> 8) == (b >> 8))) ? 1u : 0u;
        a = ps[r4.w]; b = ps[c4.w];
        local += (((a & 0xffu) == (b & 0xffu)) == ((a >> 8) == (b >> 8))) ? 1u : 0u;
    }
    if (local) atomicAdd(cnt, local);
}

__global__ void k_fin(const unsigned int* __restrict__ cnt, float* __restrict__ out) {
    out[0] = (float)(*cnt) / (float)N_EDGES;
}

extern "C" void kernel_launch(void* const* d_in, const int* in_sizes, int n_in,
                              void* d_out, int out_size, void* d_ws, size_t ws_size,
                              hipStream_t stream) {
    const float* x  = (const float*)d_in[0];
    const int*   ei = (const int*)d_in[1];
    const int*   y  = (const int*)d_in[2];
    const float* W1 = (const float*)d_in[3];
    const float* b1 = (const float*)d_in[4];
    const float* W2 = (const float*)d_in[5];
    const float* b2 = (const float*)d_in[6];

    const int* row = ei;             // edge_index[0]
    const int* col = ei + N_EDGES;   // edge_index[1]

    float* ws = (float*)d_ws;
    // workspace layout (4B units)
    __half* h1s   = (__half*)ws;                    // N*64 fp16  -> 3.2M units
    __half* h2s   = (__half*)(ws + 3200000);        // N*64 fp16 (padded) -> 3.2M units
    float* dinv   = ws + 6400000;                   // N
    int*   deg    = (int*)(ws + 6500000);           // N
    int*   off    = (int*)(ws + 6600000);           // N
    int*   srow   = (int*)(ws + 6700000);           // E (3.2M)
    int*   ghist  = (int*)(ws + 9900000);           // 512*256
    int*   goff   = (int*)(ws + 10050000);          // 512*256
    int*   bbase  = (int*)(ws + 10200000);          // 256
    int*   bend   = (int*)(ws + 10201000);          // 256
    unsigned short* ps = (unsigned short*)(ws + 10300000);  // N ushort
    unsigned int* cnt  = (unsigned int*)(ws + 10400000);
    unsigned int* epair = (unsigned int*)(ws + 10500000);   // E uint32 (3.2M)
    float* o1     = ws + 10500000;                  // N*64 fp32 (6.4M) — reuses epair after k_B

    float* out = (float*)d_out;   // logp [N*40], p [N*40], ratio [1]

    hipMemsetAsync(cnt, 0, 4, stream);

    const int GEMM_GRID = (N_NODES + 127) / 128;

    k_A1<<<NBLK_A, 256, 0, stream>>>(col, ghist);
    k_A2<<<1, 256, 0, stream>>>(ghist, goff, bbase, bend);
    k_A3<<<NBLK_A, 256, 0, stream>>>(row, col, goff, epair);
    k_B<<<NBUCK, 256, 0, stream>>>(epair, bbase, bend, off, deg, dinv, srow);
    k_gemm<F_IN, HID, HID, 128><<<GEMM_GRID, 256, 0, stream>>>(x, W1, dinv, h1s);
    k_agg1<<<(N_NODES * 64 + 255) / 256, 256, 0, stream>>>(off, deg, srow, dinv, h1s, b1, o1);
    k_gemm<HID, N_CLASS, H2S, 128><<<GEMM_GRID, 256, 0, stream>>>(o1, W2, dinv, h2s);
    k_agg2<<<(N_NODES * 64 + 255) / 256, 256, 0, stream>>>(off, deg, srow, dinv, h2s, b2, y, out, ps);
    k_ratio<<<2048, 256, 0, stream>>>(row, col, ps, cnt);
    k_fin<<<1, 1, 0, stream>>>(cnt, out + (size_t)2 * N_NODES * N_CLASS);
}

// Round 12
// 497.272 us; speedup vs baseline: 3.9047x; 1.1592x over previous
//
#include <hip/hip_runtime.h>
#include <hip/hip_fp16.h>

#define N_NODES 100000
#define N_EDGES 3200000
#define F_IN 128
#define HID 64
#define N_CLASS 40
#define H2S 64             // padded stride for h2 rows (one 128B line)

#define NBUCK 196          // ceil(100000/512)
#define BSHIFT 9           // bucket = col >> 9, local = col & 511
#define NBLK_A 512
#define CHUNK_A ((N_EDGES + NBLK_A - 1) / NBLK_A)   // 6250

// ---------------- Phase A1: per-block bucket histogram ----------------
__global__ __launch_bounds__(256) void k_A1(const int* __restrict__ col, int* __restrict__ ghist) {
    __shared__ int hist[256];
    int t = threadIdx.x;
    hist[t] = 0;
    __syncthreads();
    int e0 = blockIdx.x * CHUNK_A;
    int e1 = e0 + CHUNK_A; if (e1 > N_EDGES) e1 = N_EDGES;
    for (int e = e0 + t; e < e1; e += 256) {
        atomicAdd(&hist[col[e] >> BSHIFT], 1);
    }
    __syncthreads();
    ghist[blockIdx.x * 256 + t] = hist[t];
}

// ---------------- Phase A2: scan -> per-block bucket offsets ----------------
__global__ __launch_bounds__(256) void k_A2(const int* __restrict__ ghist, int* __restrict__ goff,
                                            int* __restrict__ bbase, int* __restrict__ bend) {
    __shared__ int sums[256];
    int b = threadIdx.x;
    int tot = 0;
    for (int k = 0; k < NBLK_A; ++k) tot += ghist[k * 256 + b];
    sums[b] = tot;
    __syncthreads();
    for (int d = 1; d < 256; d <<= 1) {
        int o = (b >= d) ? sums[b - d] : 0;
        __syncthreads();
        sums[b] += o;
        __syncthreads();
    }
    int base = sums[b] - tot;   // exclusive
    bbase[b] = base;
    bend[b] = base + tot;
    int run = base;
    for (int k = 0; k < NBLK_A; ++k) {
        goff[k * 256 + b] = run;
        run += ghist[k * 256 + b];
    }
}

// ---------------- Phase A3: coalesced-reserved bucket scatter (packed key) ----------------
__global__ __launch_bounds__(256) void k_A3(const int* __restrict__ row, const int* __restrict__ col,
                                            const int* __restrict__ goff, unsigned int* __restrict__ epair) {
    __shared__ int cur[256];
    int t = threadIdx.x;
    cur[t] = goff[blockIdx.x * 256 + t];
    __syncthreads();
    int e0 = blockIdx.x * CHUNK_A;
    int e1 = e0 + CHUNK_A; if (e1 > N_EDGES) e1 = N_EDGES;
    for (int e = e0 + t; e < e1; e += 256) {
        int c = col[e];
        int pos = atomicAdd(&cur[c >> BSHIFT], 1);
        epair[pos] = ((unsigned int)(c & 511) << 17) | (unsigned int)row[e];
    }
}

// ---------------- Phase B: per-bucket CSR build + srow scatter (L2-local) ----------------
__global__ __launch_bounds__(256) void k_B(const unsigned int* __restrict__ epair,
                                           const int* __restrict__ bbase, const int* __restrict__ bend,
                                           int* __restrict__ off, int* __restrict__ deg,
                                           float* __restrict__ dinv, int* __restrict__ srow) {
    __shared__ int h[512];
    __shared__ int psc[256];
    int t = threadIdx.x;
    int b = blockIdx.x;
    int n0 = b << BSHIFT;
    int e0 = bbase[b], e1 = bend[b];
    h[t] = 0; h[t + 256] = 0;
    __syncthreads();
    for (int e = e0 + t; e < e1; e += 256) {
        atomicAdd(&h[epair[e] >> 17], 1);
    }
    __syncthreads();
    int a0 = h[2 * t], a1 = h[2 * t + 1];
    psc[t] = a0 + a1;
    __syncthreads();
    for (int d = 1; d < 256; d <<= 1) {
        int o = (t >= d) ? psc[t - d] : 0;
        __syncthreads();
        psc[t] += o;
        __syncthreads();
    }
    int base0 = e0 + psc[t] - (a0 + a1);
    h[2 * t] = base0;
    h[2 * t + 1] = base0 + a0;
    int n = n0 + 2 * t;
    if (n < N_NODES) {
        off[n] = base0; deg[n] = a0; dinv[n] = rsqrtf((float)a0 + 1.0f);
    }
    if (n + 1 < N_NODES) {
        off[n + 1] = base0 + a0; deg[n + 1] = a1; dinv[n + 1] = rsqrtf((float)a1 + 1.0f);
    }
    __syncthreads();
    for (int e = e0 + t; e < e1; e += 256) {
        unsigned int k = epair[e];
        int c = k >> 17;
        int pos = atomicAdd(&h[c], 1);
        srow[pos] = (int)(k & 0x1FFFFu);
    }
}

// ---------------- tiled dense GEMM: O[N][OS] = scale[n] * (X @ W^T), fp16 out ----------------
// unroll capped at 2 + launch_bounds(256,4): keeps VGPR <=128 so 4+ waves/EU hide LDS latency
template<int K, int C, int OS, int ROWS_PB>
__global__ __launch_bounds__(256, 4) void k_gemm(const float* __restrict__ X, const float* __restrict__ W,
                                                 const float* __restrict__ scale, __half* __restrict__ O) {
    constexpr int PK = K + 4;
    __shared__ float ws[C * PK];
    __shared__ float xs[32 * PK];
    int t = threadIdx.x;
    for (int i4 = t; i4 < C * K / 4; i4 += 256) {
        int j = i4 / (K / 4);
        int k4 = i4 % (K / 4);
        float4 v = ((const float4*)W)[i4];
        *(float4*)&ws[j * PK + k4 * 4] = v;
    }
    int j = t & 63;
    int r0 = (t >> 6) * 8;
    int rowbase = blockIdx.x * ROWS_PB;
    for (int chunk = 0; chunk < ROWS_PB; chunk += 32) {
        int cb = rowbase + chunk;
        __syncthreads();
        for (int i4 = t; i4 < 32 * K / 4; i4 += 256) {
            int r = i4 / (K / 4);
            int k4 = i4 % (K / 4);
            int rr = cb + r;
            float4 v = make_float4(0.f, 0.f, 0.f, 0.f);
            if (rr < N_NODES) v = ((const float4*)X)[(size_t)rr * (K / 4) + k4];
            *(float4*)&xs[r * PK + k4 * 4] = v;
        }
        __syncthreads();
        if (j < C) {
            float acc[8] = {0.f, 0.f, 0.f, 0.f, 0.f, 0.f, 0.f, 0.f};
#pragma unroll 2
            for (int k4 = 0; k4 < K / 4; ++k4) {
                float4 wv = *(const float4*)&ws[j * PK + k4 * 4];
#pragma unroll
                for (int r = 0; r < 8; ++r) {
                    float4 xv = *(const float4*)&xs[(r0 + r) * PK + k4 * 4];
                    acc[r] += xv.x * wv.x + xv.y * wv.y + xv.z * wv.z + xv.w * wv.w;
                }
            }
#pragma unroll
            for (int r = 0; r < 8; ++r) {
                int rr = cb + r0 + r;
                if (rr < N_NODES) O[(size_t)rr * OS + j] = __float2half(acc[r] * scale[rr]);
            }
        }
    }
}

// ---------------- layer-1 aggregation: forced 8-deep gather pipeline ----------------
__global__ __launch_bounds__(256) void k_agg1(const int* __restrict__ off, const int* __restrict__ deg,
                                              const int* __restrict__ srow, const float* __restrict__ dinv,
                                              const __half* __restrict__ h1s, const float* __restrict__ b1,
                                              float* __restrict__ o1) {
    int node = (blockIdx.x * 256 + threadIdx.x) >> 6;
    int lane = threadIdx.x & 63;
    if (node >= N_NODES) return;
    int start = off[node];
    int end = start + deg[node];
    float acc = 0.f;
    int j = start;
    int nb = (end - start) >> 3;
    if (nb > 0) {
        int idx[8];
#pragma unroll
        for (int k = 0; k < 8; ++k) idx[k] = srow[j + k];
        for (int b = 1; b <= nb; ++b) {
            __half raw[8];
#pragma unroll
            for (int k = 0; k < 8; ++k) raw[k] = h1s[(size_t)idx[k] * HID + lane];   // 8 independent gathers
            int jn = j + 8;
            if (b < nb) {
#pragma unroll
                for (int k = 0; k < 8; ++k) idx[k] = srow[jn + k];                   // prefetch next indices
            }
            __builtin_amdgcn_sched_barrier(0);   // loads may not sink below this point
#pragma unroll
            for (int k = 0; k < 8; ++k) acc += __half2float(raw[k]);
            j = jn;
        }
    }
    for (; j < end; ++j) acc += __half2float(h1s[(size_t)srow[j] * HID + lane]);
    float dc = dinv[node];
    float v = dc * (acc + __half2float(h1s[(size_t)node * HID + lane])) + b1[lane];
    o1[(size_t)node * HID + lane] = v > 0.f ? v : 0.f;
}

// ---------------- layer-2 aggregation + softmax/logsoftmax/argmax ----------------
__global__ __launch_bounds__(256) void k_agg2(const int* __restrict__ off, const int* __restrict__ deg,
                                              const int* __restrict__ srow, const float* __restrict__ dinv,
                                              const __half* __restrict__ h2s, const float* __restrict__ b2,
                                              const int* __restrict__ y,
                                              float* __restrict__ out, unsigned short* __restrict__ ps) {
    int node = (blockIdx.x * 256 + threadIdx.x) >> 6;
    int lane = threadIdx.x & 63;
    if (node >= N_NODES) return;
    int start = off[node];
    int end = start + deg[node];
    int cl = lane < N_CLASS ? lane : N_CLASS - 1;   // unconditional loads, lanes 40-63 mirror lane 39
    bool act = lane < N_CLASS;
    float acc = 0.f;
    int j = start;
    int nb = (end - start) >> 3;
    if (nb > 0) {
        int idx[8];
#pragma unroll
        for (int k = 0; k < 8; ++k) idx[k] = srow[j + k];
        for (int b = 1; b <= nb; ++b) {
            __half raw[8];
#pragma unroll
            for (int k = 0; k < 8; ++k) raw[k] = h2s[(size_t)idx[k] * H2S + cl];
            int jn = j + 8;
            if (b < nb) {
#pragma unroll
                for (int k = 0; k < 8; ++k) idx[k] = srow[jn + k];
            }
            __builtin_amdgcn_sched_barrier(0);
#pragma unroll
            for (int k = 0; k < 8; ++k) acc += __half2float(raw[k]);
            j = jn;
        }
    }
    for (; j < end; ++j) acc += __half2float(h2s[(size_t)srow[j] * H2S + cl]);
    float dc = dinv[node];
    float v = -1e30f;
    if (act) v = dc * (acc + __half2float(h2s[(size_t)node * H2S + cl])) + b2[lane];
    float m = v;
#pragma unroll
    for (int k = 1; k < 64; k <<= 1) {
        float o = __shfl_xor(m, k);
        m = o > m ? o : m;
    }
    float sv = act ? expf(v - m) : 0.f;
    float s = sv;
#pragma unroll
    for (int k = 1; k < 64; k <<= 1) s += __shfl_xor(s, k);
    float ls = logf(s);
    float av = v;
    int ai = act ? lane : 64;
#pragma unroll
    for (int k = 1; k < 64; k <<= 1) {
        float ov = __shfl_xor(av, k);
        int oi = __shfl_xor(ai, k);
        if (ov > av || (ov == av && oi < ai)) { av = ov; ai = oi; }
    }
    if (act) {
        float lp = (v - m) - ls;
        float* logp = out;
        float* p = out + (size_t)N_NODES * N_CLASS;
        logp[(size_t)node * N_CLASS + lane] = lp;
        p[(size_t)node * N_CLASS + lane] = expf(lp);
    }
    if (lane == 0) ps[node] = (unsigned short)((y[node] << 8) | ai);
}

// ---------------- ratio over original edges (packed y|pred gather, int4 edges) ----------------
__global__ __launch_bounds__(256) void k_ratio(const int* __restrict__ row, const int* __restrict__ col,
                                               const unsigned short* __restrict__ ps,
                                               unsigned int* __restrict__ cnt) {
    int i = blockIdx.x * 256 + threadIdx.x;
    int stride = gridDim.x * 256;
    unsigned int local = 0;
    for (int e4 = i; e4 < N_EDGES / 4; e4 += stride) {
        int4 r4 = ((const int4*)row)[e4];
        int4 c4 = ((const int4*)col)[e4];
        unsigned int a, b;
        a = ps[r4.x]; b = ps[c4.x];
        local += (((a & 0xffu) == (b & 0xffu)) == ((a >> 8) == (b >> 8))) ? 1u : 0u;
        a = ps[r4.y]; b = ps[c4.y];
        local += (((a & 0xffu) == (b & 0xffu)) == ((a >> 8) == (b >> 8))) ? 1u : 0u;
        a = ps[r4.z]; b = ps[c4.z];
        local += (((a & 0xffu) == (b & 0xffu)) == ((a >> 8) == (b >> 8))) ? 1u : 0u;
        a = ps[r4.w]; b = ps[c4.w];
        local += (((a & 0xffu) == (b & 0xffu)) == ((a >> 8) == (b >> 8))) ? 1u : 0u;
    }
    if (local) atomicAdd(cnt, local);
}

__global__ void k_fin(const unsigned int* __restrict__ cnt, float* __restrict__ out) {
    out[0] = (float)(*cnt) / (float)N_EDGES;
}

extern "C" void kernel_launch(void* const* d_in, const int* in_sizes, int n_in,
                              void* d_out, int out_size, void* d_ws, size_t ws_size,
                              hipStream_t stream) {
    const float* x  = (const float*)d_in[0];
    const int*   ei = (const int*)d_in[1];
    const int*   y  = (const int*)d_in[2];
    const float* W1 = (const float*)d_in[3];
    const float* b1 = (const float*)d_in[4];
    const float* W2 = (const float*)d_in[5];
    const float* b2 = (const float*)d_in[6];

    const int* row = ei;             // edge_index[0]
    const int* col = ei + N_EDGES;   // edge_index[1]

    float* ws = (float*)d_ws;
    // workspace layout (4B units)
    __half* h1s   = (__half*)ws;                    // N*64 fp16  -> 3.2M units
    __half* h2s   = (__half*)(ws + 3200000);        // N*64 fp16 (padded) -> 3.2M units
    float* dinv   = ws + 6400000;                   // N
    int*   deg    = (int*)(ws + 6500000);           // N
    int*   off    = (int*)(ws + 6600000);           // N
    int*   srow   = (int*)(ws + 6700000);           // E (3.2M)
    int*   ghist  = (int*)(ws + 9900000);           // 512*256
    int*   goff   = (int*)(ws + 10050000);          // 512*256
    int*   bbase  = (int*)(ws + 10200000);          // 256
    int*   bend   = (int*)(ws + 10201000);          // 256
    unsigned short* ps = (unsigned short*)(ws + 10300000);  // N ushort
    unsigned int* cnt  = (unsigned int*)(ws + 10400000);
    unsigned int* epair = (unsigned int*)(ws + 10500000);   // E uint32 (3.2M)
    float* o1     = ws + 10500000;                  // N*64 fp32 (6.4M) — reuses epair after k_B

    float* out = (float*)d_out;   // logp [N*40], p [N*40], ratio [1]

    hipMemsetAsync(cnt, 0, 4, stream);

    const int GEMM_GRID = (N_NODES + 127) / 128;

    k_A1<<<NBLK_A, 256, 0, stream>>>(col, ghist);
    k_A2<<<1, 256, 0, stream>>>(ghist, goff, bbase, bend);
    k_A3<<<NBLK_A, 256, 0, stream>>>(row, col, goff, epair);
    k_B<<<NBUCK, 256, 0, stream>>>(epair, bbase, bend, off, deg, dinv, srow);
    k_gemm<F_IN, HID, HID, 128><<<GEMM_GRID, 256, 0, stream>>>(x, W1, dinv, h1s);
    k_agg1<<<(N_NODES * 64 + 255) / 256, 256, 0, stream>>>(off, deg, srow, dinv, h1s, b1, o1);
    k_gemm<HID, N_CLASS, H2S, 128><<<GEMM_GRID, 256, 0, stream>>>(o1, W2, dinv, h2s);
    k_agg2<<<(N_NODES * 64 + 255) / 256, 256, 0, stream>>>(off, deg, srow, dinv, h2s, b2, y, out, ps);
    k_ratio<<<2048, 256, 0, stream>>>(row, col, ps, cnt);
    k_fin<<<1, 1, 0, stream>>>(cnt, out + (size_t)2 * N_NODES * N_CLASS);
}

// Round 13
// 479.493 us; speedup vs baseline: 4.0494x; 1.0371x over previous
//
#include <hip/hip_runtime.h>
#include <hip/hip_fp16.h>

#define N_NODES 100000
#define N_EDGES 3200000
#define F_IN 128
#define HID 64
#define N_CLASS 40
#define ZROW N_NODES       // sentinel zero-row index

#define NBUCK 196          // ceil(100000/512)
#define BSHIFT 9
#define NBLK_A 512
#define CHUNK_A ((N_EDGES + NBLK_A - 1) / NBLK_A)

#if defined(__has_builtin)
#  if __has_builtin(__builtin_amdgcn_fdot2)
#    define HAS_FDOT2 1
#  endif
#endif
typedef _Float16 h2v __attribute__((ext_vector_type(2)));

// ---------------- Phase A1: per-block bucket histogram ----------------
__global__ __launch_bounds__(256) void k_A1(const int* __restrict__ col, int* __restrict__ ghist) {
    __shared__ int hist[256];
    int t = threadIdx.x;
    hist[t] = 0;
    __syncthreads();
    int e0 = blockIdx.x * CHUNK_A;
    int e1 = e0 + CHUNK_A; if (e1 > N_EDGES) e1 = N_EDGES;
    for (int e = e0 + t; e < e1; e += 256) {
        atomicAdd(&hist[col[e] >> BSHIFT], 1);
    }
    __syncthreads();
    ghist[blockIdx.x * 256 + t] = hist[t];
}

// ---------------- Phase A2: scan -> per-block bucket offsets ----------------
__global__ __launch_bounds__(256) void k_A2(const int* __restrict__ ghist, int* __restrict__ goff,
                                            int* __restrict__ bbase, int* __restrict__ bend) {
    __shared__ int sums[256];
    int b = threadIdx.x;
    int tot = 0;
    for (int k = 0; k < NBLK_A; ++k) tot += ghist[k * 256 + b];
    sums[b] = tot;
    __syncthreads();
    for (int d = 1; d < 256; d <<= 1) {
        int o = (b >= d) ? sums[b - d] : 0;
        __syncthreads();
        sums[b] += o;
        __syncthreads();
    }
    int base = sums[b] - tot;
    bbase[b] = base;
    bend[b] = base + tot;
    int run = base;
    for (int k = 0; k < NBLK_A; ++k) {
        goff[k * 256 + b] = run;
        run += ghist[k * 256 + b];
    }
}

// ---------------- Phase A3: coalesced-reserved bucket scatter ----------------
__global__ __launch_bounds__(256) void k_A3(const int* __restrict__ row, const int* __restrict__ col,
                                            const int* __restrict__ goff, unsigned int* __restrict__ epair) {
    __shared__ int cur[256];
    int t = threadIdx.x;
    cur[t] = goff[blockIdx.x * 256 + t];
    __syncthreads();
    int e0 = blockIdx.x * CHUNK_A;
    int e1 = e0 + CHUNK_A; if (e1 > N_EDGES) e1 = N_EDGES;
    for (int e = e0 + t; e < e1; e += 256) {
        int c = col[e];
        int pos = atomicAdd(&cur[c >> BSHIFT], 1);
        epair[pos] = ((unsigned int)(c & 511) << 17) | (unsigned int)row[e];
    }
}

// ---------------- Phase B: per-bucket CSR build, degrees padded to x8 ----------------
__global__ __launch_bounds__(256) void k_B(const unsigned int* __restrict__ epair,
                                           const int* __restrict__ bbase, const int* __restrict__ bend,
                                           int* __restrict__ off, int* __restrict__ pdeg,
                                           float* __restrict__ dinv, int* __restrict__ srow) {
    __shared__ int h[512];
    __shared__ int psc[256];
    int t = threadIdx.x;
    int b = blockIdx.x;
    int n0 = b << BSHIFT;
    int e0 = bbase[b], e1 = bend[b];
    int pbase = e0 + b * 4096;    // padded region base (<=3584 pad per bucket)
    h[t] = 0; h[t + 256] = 0;
    __syncthreads();
    for (int e = e0 + t; e < e1; e += 256) {
        atomicAdd(&h[epair[e] >> 17], 1);
    }
    __syncthreads();
    int a0 = h[2 * t], a1 = h[2 * t + 1];
    int p0 = (a0 + 7) & ~7, p1 = (a1 + 7) & ~7;
    psc[t] = p0 + p1;
    __syncthreads();
    for (int d = 1; d < 256; d <<= 1) {
        int o = (t >= d) ? psc[t - d] : 0;
        __syncthreads();
        psc[t] += o;
        __syncthreads();
    }
    int base0 = pbase + psc[t] - (p0 + p1);
    int base1 = base0 + p0;
    h[2 * t] = base0;
    h[2 * t + 1] = base1;
    int n = n0 + 2 * t;
    if (n < N_NODES) {
        off[n] = base0; pdeg[n] = p0; dinv[n] = rsqrtf((float)a0 + 1.0f);
        for (int p = a0; p < p0; ++p) srow[base0 + p] = ZROW;
    }
    if (n + 1 < N_NODES) {
        off[n + 1] = base1; pdeg[n + 1] = p1; dinv[n + 1] = rsqrtf((float)a1 + 1.0f);
        for (int p = a1; p < p1; ++p) srow[base1 + p] = ZROW;
    }
    __syncthreads();
    for (int e = e0 + t; e < e1; e += 256) {
        unsigned int k = epair[e];
        int c = k >> 17;
        int pos = atomicAdd(&h[c], 1);
        srow[pos] = (int)(k & 0x1FFFFu);
    }
}

// ---------------- zero the sentinel rows ----------------
__global__ void k_zrow(__half* __restrict__ h1s, __half* __restrict__ o1s) {
    int t = threadIdx.x;
    if (t < 64) h1s[(size_t)ZROW * 64 + t] = __float2half(0.f);
    else        o1s[(size_t)ZROW * 64 + (t - 64)] = __float2half(0.f);
}

// ---------------- tiled dense GEMM (layer 1): O = scale[n]*(X @ W^T), fp16 ----------------
template<int K, int C, int OS, int ROWS_PB>
__global__ __launch_bounds__(256, 4) void k_gemm(const float* __restrict__ X, const float* __restrict__ W,
                                                 const float* __restrict__ scale, __half* __restrict__ O) {
    constexpr int PK = K + 4;
    __shared__ float ws[C * PK];
    __shared__ float xs[32 * PK];
    int t = threadIdx.x;
    for (int i4 = t; i4 < C * K / 4; i4 += 256) {
        int j = i4 / (K / 4);
        int k4 = i4 % (K / 4);
        float4 v = ((const float4*)W)[i4];
        *(float4*)&ws[j * PK + k4 * 4] = v;
    }
    int j = t & 63;
    int r0 = (t >> 6) * 8;
    int rowbase = blockIdx.x * ROWS_PB;
    for (int chunk = 0; chunk < ROWS_PB; chunk += 32) {
        int cb = rowbase + chunk;
        __syncthreads();
        for (int i4 = t; i4 < 32 * K / 4; i4 += 256) {
            int r = i4 / (K / 4);
            int k4 = i4 % (K / 4);
            int rr = cb + r;
            float4 v = make_float4(0.f, 0.f, 0.f, 0.f);
            if (rr < N_NODES) v = ((const float4*)X)[(size_t)rr * (K / 4) + k4];
            *(float4*)&xs[r * PK + k4 * 4] = v;
        }
        __syncthreads();
        if (j < C) {
            float acc[8] = {0.f, 0.f, 0.f, 0.f, 0.f, 0.f, 0.f, 0.f};
#pragma unroll 2
            for (int k4 = 0; k4 < K / 4; ++k4) {
                float4 wv = *(const float4*)&ws[j * PK + k4 * 4];
#pragma unroll
                for (int r = 0; r < 8; ++r) {
                    float4 xv = *(const float4*)&xs[(r0 + r) * PK + k4 * 4];
                    acc[r] += xv.x * wv.x + xv.y * wv.y + xv.z * wv.z + xv.w * wv.w;
                }
            }
#pragma unroll
            for (int r = 0; r < 8; ++r) {
                int rr = cb + r0 + r;
                if (rr < N_NODES) O[(size_t)rr * OS + j] = __float2half(acc[r] * scale[rr]);
            }
        }
    }
}

// consume one dwordx4 (8 halves) into 8 f32 accumulators
#define CONSUME(RAW) do { \
    __half2 q0 = *(__half2*)&RAW.x, q1 = *(__half2*)&RAW.y; \
    __half2 q2 = *(__half2*)&RAW.z, q3 = *(__half2*)&RAW.w; \
    float2 f0 = __half22float2(q0), f1 = __half22float2(q1); \
    float2 f2 = __half22float2(q2), f3 = __half22float2(q3); \
    a0 += f0.x; a1 += f0.y; a2 += f1.x; a3 += f1.y; \
    a4 += f2.x; a5 += f2.y; a6 += f3.x; a7 += f3.y; } while (0)

// ---------------- layer-1 aggregation: 8-edge x 8-seg dwordx4 gathers ----------------
__global__ __launch_bounds__(256) void k_agg1(const int* __restrict__ off, const int* __restrict__ pdeg,
                                              const int* __restrict__ srow, const float* __restrict__ dinv,
                                              const __half* __restrict__ h1s, const float* __restrict__ b1,
                                              __half* __restrict__ o1s) {
    __shared__ float sh[4][64];
    int t = threadIdx.x;
    int node = (blockIdx.x * 256 + t) >> 6;
    int lane = t & 63, wid = t >> 6;
    int e = lane >> 3, seg = lane & 7;
    int start = off[node];
    int nb = pdeg[node] >> 3;
    float a0=0,a1=0,a2=0,a3=0,a4=0,a5=0,a6=0,a7=0;
    int j = start;
    if (nb > 0) {
        int src = srow[j + e];
        uint4 raw = *(const uint4*)(h1s + ((size_t)src << 6) + (seg << 3));
        for (int b = 1; b < nb; ++b) {
            int nsrc = srow[j + 8 + e];
            uint4 nraw = *(const uint4*)(h1s + ((size_t)nsrc << 6) + (seg << 3));
            __builtin_amdgcn_sched_barrier(0);
            CONSUME(raw);
            raw = nraw; j += 8;
        }
        CONSUME(raw);
    }
    if (e == 0) {   // self term, counted once (pre-reduce, one e-group)
        uint4 sraw = *(const uint4*)(h1s + ((size_t)node << 6) + (seg << 3));
        CONSUME(sraw);
    }
#pragma unroll
    for (int m = 8; m < 64; m <<= 1) {
        a0 += __shfl_xor(a0, m); a1 += __shfl_xor(a1, m);
        a2 += __shfl_xor(a2, m); a3 += __shfl_xor(a3, m);
        a4 += __shfl_xor(a4, m); a5 += __shfl_xor(a5, m);
        a6 += __shfl_xor(a6, m); a7 += __shfl_xor(a7, m);
    }
    if (e == 0) {
        sh[wid][seg * 8 + 0] = a0; sh[wid][seg * 8 + 1] = a1;
        sh[wid][seg * 8 + 2] = a2; sh[wid][seg * 8 + 3] = a3;
        sh[wid][seg * 8 + 4] = a4; sh[wid][seg * 8 + 5] = a5;
        sh[wid][seg * 8 + 6] = a6; sh[wid][seg * 8 + 7] = a7;
    }
    __syncthreads();
    float dc = dinv[node];
    float v = dc * sh[wid][lane] + b1[lane];
    o1s[(size_t)node * 64 + lane] = __float2half(dc * (v > 0.f ? v : 0.f));
}

// ---------------- layer-2: gather o1s + fused W2 matvec + softmax/argmax ----------------
__global__ __launch_bounds__(256) void k_agg2(const int* __restrict__ off, const int* __restrict__ pdeg,
                                              const int* __restrict__ srow, const float* __restrict__ dinv,
                                              const __half* __restrict__ o1s,
                                              const float* __restrict__ W2, const float* __restrict__ b2,
                                              const int* __restrict__ y,
                                              float* __restrict__ out, unsigned short* __restrict__ ps) {
    __shared__ __half w2h[32 * 80];   // [k2][c] half-pairs: slot (k2*40+c)*2 + (k&1)
    __shared__ __half shh[4][64];
    int t = threadIdx.x;
    for (int i = t; i < HID * N_CLASS; i += 256) {
        int c = i >> 6, k = i & 63;
        w2h[(k >> 1) * 80 + c * 2 + (k & 1)] = __float2half(W2[i]);
    }
    int node = (blockIdx.x * 256 + t) >> 6;
    int lane = t & 63, wid = t >> 6;
    int e = lane >> 3, seg = lane & 7;
    int start = off[node];
    int nb = pdeg[node] >> 3;
    float a0=0,a1=0,a2=0,a3=0,a4=0,a5=0,a6=0,a7=0;
    int j = start;
    if (nb > 0) {
        int src = srow[j + e];
        uint4 raw = *(const uint4*)(o1s + ((size_t)src << 6) + (seg << 3));
        for (int b = 1; b < nb; ++b) {
            int nsrc = srow[j + 8 + e];
            uint4 nraw = *(const uint4*)(o1s + ((size_t)nsrc << 6) + (seg << 3));
            __builtin_amdgcn_sched_barrier(0);
            CONSUME(raw);
            raw = nraw; j += 8;
        }
        CONSUME(raw);
    }
    if (e == 0) {   // self term: + o1s[node]
        uint4 sraw = *(const uint4*)(o1s + ((size_t)node << 6) + (seg << 3));
        CONSUME(sraw);
    }
#pragma unroll
    for (int m = 8; m < 64; m <<= 1) {
        a0 += __shfl_xor(a0, m); a1 += __shfl_xor(a1, m);
        a2 += __shfl_xor(a2, m); a3 += __shfl_xor(a3, m);
        a4 += __shfl_xor(a4, m); a5 += __shfl_xor(a5, m);
        a6 += __shfl_xor(a6, m); a7 += __shfl_xor(a7, m);
    }
    if (e == 0) {
        shh[wid][seg * 8 + 0] = __float2half(a0); shh[wid][seg * 8 + 1] = __float2half(a1);
        shh[wid][seg * 8 + 2] = __float2half(a2); shh[wid][seg * 8 + 3] = __float2half(a3);
        shh[wid][seg * 8 + 4] = __float2half(a4); shh[wid][seg * 8 + 5] = __float2half(a5);
        shh[wid][seg * 8 + 6] = __float2half(a6); shh[wid][seg * 8 + 7] = __float2half(a7);
    }
    __syncthreads();   // covers w2h staging + shh transpose
    bool act = lane < N_CLASS;
    int cl = act ? lane : N_CLASS - 1;
    float mv = 0.f;
    const __half2* iv = (const __half2*)shh[wid];
#pragma unroll 8
    for (int k2 = 0; k2 < 32; ++k2) {
        __half2 av = iv[k2];
        __half2 wv = *(const __half2*)&w2h[k2 * 80 + cl * 2];
#ifdef HAS_FDOT2
        mv = __builtin_amdgcn_fdot2(*(h2v*)&av, *(h2v*)&wv, mv, false);
#else
        float2 fa = __half22float2(av), fw = __half22float2(wv);
        mv += fa.x * fw.x + fa.y * fw.y;
#endif
    }
    float dc = dinv[node];
    float v = act ? (dc * mv + b2[lane]) : -1e30f;
    float m = v;
#pragma unroll
    for (int k = 1; k < 64; k <<= 1) {
        float o = __shfl_xor(m, k);
        m = o > m ? o : m;
    }
    float sv = act ? expf(v - m) : 0.f;
    float s = sv;
#pragma unroll
    for (int k = 1; k < 64; k <<= 1) s += __shfl_xor(s, k);
    float ls = logf(s);
    float av2 = v;
    int ai = act ? lane : 64;
#pragma unroll
    for (int k = 1; k < 64; k <<= 1) {
        float ov = __shfl_xor(av2, k);
        int oi = __shfl_xor(ai, k);
        if (ov > av2 || (ov == av2 && oi < ai)) { av2 = ov; ai = oi; }
    }
    if (act) {
        float lp = (v - m) - ls;
        float* logp = out;
        float* p = out + (size_t)N_NODES * N_CLASS;
        logp[(size_t)node * N_CLASS + lane] = lp;
        p[(size_t)node * N_CLASS + lane] = expf(lp);
    }
    if (lane == 0) ps[node] = (unsigned short)((y[node] << 8) | ai);
}

// ---------------- ratio over original edges ----------------
__global__ __launch_bounds__(256) void k_ratio(const int* __restrict__ row, const int* __restrict__ col,
                                               const unsigned short* __restrict__ ps,
                                               unsigned int* __restrict__ cnt) {
    int i = blockIdx.x * 256 + threadIdx.x;
    int stride = gridDim.x * 256;
    unsigned int local = 0;
    for (int e4 = i; e4 < N_EDGES / 4; e4 += stride) {
        int4 r4 = ((const int4*)row)[e4];
        int4 c4 = ((const int4*)col)[e4];
        unsigned int a, b;
        a = ps[r4.x]; b = ps[c4.x];
        local += (((a & 0xffu) == (b & 0xffu)) == ((a >> 8) == (b >> 8))) ? 1u : 0u;
        a = ps[r4.y]; b = ps[c4.y];
        local += (((a & 0xffu) == (b & 0xffu)) == ((a >> 8) == (b >> 8))) ? 1u : 0u;
        a = ps[r4.z]; b = ps[c4.z];
        local += (((a & 0xffu) == (b & 0xffu)) == ((a >> 8) == (b >> 8))) ? 1u : 0u;
        a = ps[r4.w]; b = ps[c4.w];
        local += (((a & 0xffu) == (b & 0xffu)) == ((a >> 8) == (b >> 8))) ? 1u : 0u;
    }
    if (local) atomicAdd(cnt, local);
}

__global__ void k_fin(const unsigned int* __restrict__ cnt, float* __restrict__ out) {
    out[0] = (float)(*cnt) / (float)N_EDGES;
}

extern "C" void kernel_launch(void* const* d_in, const int* in_sizes, int n_in,
                              void* d_out, int out_size, void* d_ws, size_t ws_size,
                              hipStream_t stream) {
    const float* x  = (const float*)d_in[0];
    const int*   ei = (const int*)d_in[1];
    const int*   y  = (const int*)d_in[2];
    const float* W1 = (const float*)d_in[3];
    const float* b1 = (const float*)d_in[4];
    const float* W2 = (const float*)d_in[5];
    const float* b2 = (const float*)d_in[6];

    const int* row = ei;
    const int* col = ei + N_EDGES;

    float* ws = (float*)d_ws;
    // workspace layout (4B units); h1s/o1s have N_NODES+1 rows (sentinel zero-row)
    __half* h1s   = (__half*)ws;                    // (N+1)*64 halves
    __half* o1s   = (__half*)(ws + 3210000);        // (N+1)*64 halves
    float* dinv   = ws + 6500000;                   // N
    int*   pdeg   = (int*)(ws + 6600000);           // N (padded degree)
    int*   off    = (int*)(ws + 6700000);           // N
    int*   srow   = (int*)(ws + 6800000);           // ~4.0M (padded CSR)
    int*   ghist  = (int*)(ws + 10900000);          // 512*256
    int*   goff   = (int*)(ws + 11100000);          // 512*256
    int*   bbase  = (int*)(ws + 11300000);          // 256
    int*   bend   = (int*)(ws + 11301000);          // 256
    unsigned short* ps = (unsigned short*)(ws + 11310000);  // N ushort
    unsigned int* cnt  = (unsigned int*)(ws + 11400000);
    unsigned int* epair = (unsigned int*)(ws + 11500000);   // E uint32

    float* out = (float*)d_out;

    hipMemsetAsync(cnt, 0, 4, stream);

    const int GEMM_GRID = (N_NODES + 127) / 128;
    const int AGG_GRID = (N_NODES * 64) / 256;      // exact: 25000

    k_A1<<<NBLK_A, 256, 0, stream>>>(col, ghist);
    k_A2<<<1, 256, 0, stream>>>(ghist, goff, bbase, bend);
    k_A3<<<NBLK_A, 256, 0, stream>>>(row, col, goff, epair);
    k_B<<<NBUCK, 256, 0, stream>>>(epair, bbase, bend, off, pdeg, dinv, srow);
    k_zrow<<<1, 128, 0, stream>>>(h1s, o1s);
    k_gemm<F_IN, HID, HID, 128><<<GEMM_GRID, 256, 0, stream>>>(x, W1, dinv, h1s);
    k_agg1<<<AGG_GRID, 256, 0, stream>>>(off, pdeg, srow, dinv, h1s, b1, o1s);
    k_agg2<<<AGG_GRID, 256, 0, stream>>>(off, pdeg, srow, dinv, o1s, W2, b2, y, out, ps);
    k_ratio<<<2048, 256, 0, stream>>>(row, col, ps, cnt);
    k_fin<<<1, 1, 0, stream>>>(cnt, out + (size_t)2 * N_NODES * N_CLASS);
}

// Round 14
// 444.504 us; speedup vs baseline: 4.3682x; 1.0787x over previous
//
#include <hip/hip_runtime.h>

#define N_NODES 100000
#define N_EDGES 3200000
#define F_IN 128
#define HID 64
#define N_CLASS 40
#define ZROW N_NODES       // sentinel zero-row index

#define NBUCK 196          // ceil(100000/512)
#define BSHIFT 9
#define NBLK_A 512
#define CHUNK_A ((N_EDGES + NBLK_A - 1) / NBLK_A)

typedef float f32x2 __attribute__((ext_vector_type(2)));

static __device__ __forceinline__ unsigned char enc_fp8(float v) {
    int w = __builtin_amdgcn_cvt_pk_fp8_f32(v, v, 0, false);
    return (unsigned char)(w & 0xff);
}

// decode 8 fp8 (uint2) and accumulate into a0..a7
#define CONSUME8(RAW) do { \
    f32x2 f0 = __builtin_amdgcn_cvt_pk_f32_fp8((int)RAW.x, false); \
    f32x2 f1 = __builtin_amdgcn_cvt_pk_f32_fp8((int)RAW.x, true); \
    f32x2 f2 = __builtin_amdgcn_cvt_pk_f32_fp8((int)RAW.y, false); \
    f32x2 f3 = __builtin_amdgcn_cvt_pk_f32_fp8((int)RAW.y, true); \
    a0 += f0.x; a1 += f0.y; a2 += f1.x; a3 += f1.y; \
    a4 += f2.x; a5 += f2.y; a6 += f3.x; a7 += f3.y; } while (0)

// ---------------- Phase A1: per-block bucket histogram ----------------
__global__ __launch_bounds__(256) void k_A1(const int* __restrict__ col, int* __restrict__ ghist) {
    __shared__ int hist[256];
    int t = threadIdx.x;
    hist[t] = 0;
    __syncthreads();
    int e0 = blockIdx.x * CHUNK_A;
    int e1 = e0 + CHUNK_A; if (e1 > N_EDGES) e1 = N_EDGES;
    for (int e = e0 + t; e < e1; e += 256) {
        atomicAdd(&hist[col[e] >> BSHIFT], 1);
    }
    __syncthreads();
    ghist[blockIdx.x * 256 + t] = hist[t];
}

// ---------------- Phase A2: scan -> per-block bucket offsets ----------------
__global__ __launch_bounds__(256) void k_A2(const int* __restrict__ ghist, int* __restrict__ goff,
                                            int* __restrict__ bbase, int* __restrict__ bend) {
    __shared__ int sums[256];
    int b = threadIdx.x;
    int tot = 0;
    for (int k = 0; k < NBLK_A; ++k) tot += ghist[k * 256 + b];
    sums[b] = tot;
    __syncthreads();
    for (int d = 1; d < 256; d <<= 1) {
        int o = (b >= d) ? sums[b - d] : 0;
        __syncthreads();
        sums[b] += o;
        __syncthreads();
    }
    int base = sums[b] - tot;
    bbase[b] = base;
    bend[b] = base + tot;
    int run = base;
    for (int k = 0; k < NBLK_A; ++k) {
        goff[k * 256 + b] = run;
        run += ghist[k * 256 + b];
    }
}

// ---------------- Phase A3: coalesced-reserved bucket scatter ----------------
__global__ __launch_bounds__(256) void k_A3(const int* __restrict__ row, const int* __restrict__ col,
                                            const int* __restrict__ goff, unsigned int* __restrict__ epair) {
    __shared__ int cur[256];
    int t = threadIdx.x;
    cur[t] = goff[blockIdx.x * 256 + t];
    __syncthreads();
    int e0 = blockIdx.x * CHUNK_A;
    int e1 = e0 + CHUNK_A; if (e1 > N_EDGES) e1 = N_EDGES;
    for (int e = e0 + t; e < e1; e += 256) {
        int c = col[e];
        int pos = atomicAdd(&cur[c >> BSHIFT], 1);
        epair[pos] = ((unsigned int)(c & 511) << 17) | (unsigned int)row[e];
    }
}

// ---------------- Phase B: per-bucket CSR build, degrees padded to x8 ----------------
__global__ __launch_bounds__(256) void k_B(const unsigned int* __restrict__ epair,
                                           const int* __restrict__ bbase, const int* __restrict__ bend,
                                           int* __restrict__ off, int* __restrict__ pdeg,
                                           float* __restrict__ dinv, int* __restrict__ srow) {
    __shared__ int h[512];
    __shared__ int psc[256];
    int t = threadIdx.x;
    int b = blockIdx.x;
    int n0 = b << BSHIFT;
    int e0 = bbase[b], e1 = bend[b];
    int pbase = e0 + b * 4096;    // padded region base (<=3584 pad per bucket)
    h[t] = 0; h[t + 256] = 0;
    __syncthreads();
    for (int e = e0 + t; e < e1; e += 256) {
        atomicAdd(&h[epair[e] >> 17], 1);
    }
    __syncthreads();
    int a0 = h[2 * t], a1 = h[2 * t + 1];
    int p0 = (a0 + 7) & ~7, p1 = (a1 + 7) & ~7;
    psc[t] = p0 + p1;
    __syncthreads();
    for (int d = 1; d < 256; d <<= 1) {
        int o = (t >= d) ? psc[t - d] : 0;
        __syncthreads();
        psc[t] += o;
        __syncthreads();
    }
    int base0 = pbase + psc[t] - (p0 + p1);
    int base1 = base0 + p0;
    h[2 * t] = base0;
    h[2 * t + 1] = base1;
    int n = n0 + 2 * t;
    if (n < N_NODES) {
        off[n] = base0; pdeg[n] = p0; dinv[n] = rsqrtf((float)a0 + 1.0f);
        for (int p = a0; p < p0; ++p) srow[base0 + p] = ZROW;
    }
    if (n + 1 < N_NODES) {
        off[n + 1] = base1; pdeg[n + 1] = p1; dinv[n + 1] = rsqrtf((float)a1 + 1.0f);
        for (int p = a1; p < p1; ++p) srow[base1 + p] = ZROW;
    }
    __syncthreads();
    for (int e = e0 + t; e < e1; e += 256) {
        unsigned int k = epair[e];
        int c = k >> 17;
        int pos = atomicAdd(&h[c], 1);
        srow[pos] = (int)(k & 0x1FFFFu);
    }
}

// ---------------- zero the sentinel rows (fp8, 64 B each) ----------------
__global__ void k_zrow(unsigned char* __restrict__ h1q, unsigned char* __restrict__ o1q) {
    int t = threadIdx.x;
    if (t < 64) h1q[(size_t)ZROW * 64 + t] = 0;
    else        o1q[(size_t)ZROW * 64 + (t - 64)] = 0;
}

// ---------------- tiled dense GEMM (layer 1): O = fp8(scale[n]*(X @ W^T)) ----------------
template<int K, int C, int ROWS_PB>
__global__ __launch_bounds__(256, 4) void k_gemm(const float* __restrict__ X, const float* __restrict__ W,
                                                 const float* __restrict__ scale, unsigned char* __restrict__ O) {
    constexpr int PK = K + 4;
    __shared__ float ws[C * PK];
    __shared__ float xs[32 * PK];
    int t = threadIdx.x;
    for (int i4 = t; i4 < C * K / 4; i4 += 256) {
        int j = i4 / (K / 4);
        int k4 = i4 % (K / 4);
        float4 v = ((const float4*)W)[i4];
        *(float4*)&ws[j * PK + k4 * 4] = v;
    }
    int j = t & 63;
    int r0 = (t >> 6) * 8;
    int rowbase = blockIdx.x * ROWS_PB;
    for (int chunk = 0; chunk < ROWS_PB; chunk += 32) {
        int cb = rowbase + chunk;
        __syncthreads();
        for (int i4 = t; i4 < 32 * K / 4; i4 += 256) {
            int r = i4 / (K / 4);
            int k4 = i4 % (K / 4);
            int rr = cb + r;
            float4 v = make_float4(0.f, 0.f, 0.f, 0.f);
            if (rr < N_NODES) v = ((const float4*)X)[(size_t)rr * (K / 4) + k4];
            *(float4*)&xs[r * PK + k4 * 4] = v;
        }
        __syncthreads();
        if (j < C) {
            float acc[8] = {0.f, 0.f, 0.f, 0.f, 0.f, 0.f, 0.f, 0.f};
#pragma unroll 2
            for (int k4 = 0; k4 < K / 4; ++k4) {
                float4 wv = *(const float4*)&ws[j * PK + k4 * 4];
#pragma unroll
                for (int r = 0; r < 8; ++r) {
                    float4 xv = *(const float4*)&xs[(r0 + r) * PK + k4 * 4];
                    acc[r] += xv.x * wv.x + xv.y * wv.y + xv.z * wv.z + xv.w * wv.w;
                }
            }
#pragma unroll
            for (int r = 0; r < 8; ++r) {
                int rr = cb + r0 + r;
                if (rr < N_NODES) O[(size_t)rr * 64 + j] = enc_fp8(acc[r] * scale[rr]);
            }
        }
    }
}

// ---------------- layer-1 aggregation: 8-edge x 8-seg fp8 gathers ----------------
__global__ __launch_bounds__(256) void k_agg1(const int* __restrict__ off, const int* __restrict__ pdeg,
                                              const int* __restrict__ srow, const float* __restrict__ dinv,
                                              const unsigned char* __restrict__ h1q, const float* __restrict__ b1,
                                              unsigned char* __restrict__ o1q) {
    __shared__ float sh[4][64];
    int t = threadIdx.x;
    int node = (blockIdx.x * 256 + t) >> 6;
    int lane = t & 63, wid = t >> 6;
    int e = lane >> 3, seg = lane & 7;
    int start = off[node];
    int nb = pdeg[node] >> 3;
    float a0=0,a1=0,a2=0,a3=0,a4=0,a5=0,a6=0,a7=0;
    int j = start;
    if (nb > 0) {
        int src = srow[j + e];
        uint2 raw = *(const uint2*)(h1q + ((size_t)src << 6) + (seg << 3));
        for (int b = 1; b < nb; ++b) {
            int nsrc = srow[j + 8 + e];
            uint2 nraw = *(const uint2*)(h1q + ((size_t)nsrc << 6) + (seg << 3));
            __builtin_amdgcn_sched_barrier(0);
            CONSUME8(raw);
            raw = nraw; j += 8;
        }
        CONSUME8(raw);
    }
    if (e == 0) {   // self term (counted once: only e-group 0)
        uint2 sraw = *(const uint2*)(h1q + ((size_t)node << 6) + (seg << 3));
        CONSUME8(sraw);
    }
#pragma unroll
    for (int m = 8; m < 64; m <<= 1) {
        a0 += __shfl_xor(a0, m); a1 += __shfl_xor(a1, m);
        a2 += __shfl_xor(a2, m); a3 += __shfl_xor(a3, m);
        a4 += __shfl_xor(a4, m); a5 += __shfl_xor(a5, m);
        a6 += __shfl_xor(a6, m); a7 += __shfl_xor(a7, m);
    }
    if (e == 0) {
        sh[wid][seg * 8 + 0] = a0; sh[wid][seg * 8 + 1] = a1;
        sh[wid][seg * 8 + 2] = a2; sh[wid][seg * 8 + 3] = a3;
        sh[wid][seg * 8 + 4] = a4; sh[wid][seg * 8 + 5] = a5;
        sh[wid][seg * 8 + 6] = a6; sh[wid][seg * 8 + 7] = a7;
    }
    __syncthreads();
    float dc = dinv[node];
    float v = dc * sh[wid][lane] + b1[lane];
    float r = v > 0.f ? v : 0.f;
    o1q[(size_t)node * 64 + lane] = enc_fp8(16.f * dc * r);   // x16: center in e4m3 range
}

// ---------------- layer-2: fp8 gather + fused W2 matvec + softmax/argmax ----------------
__global__ __launch_bounds__(256) void k_agg2(const int* __restrict__ off, const int* __restrict__ pdeg,
                                              const int* __restrict__ srow, const float* __restrict__ dinv,
                                              const unsigned char* __restrict__ o1q,
                                              const float* __restrict__ W2, const float* __restrict__ b2,
                                              const int* __restrict__ y,
                                              float* __restrict__ out, unsigned short* __restrict__ ps) {
    __shared__ float w2s[HID * 41];   // w2s[k*41+c] = W2[c][k] / 16
    __shared__ float sh[4][64];
    int t = threadIdx.x;
    for (int i = t; i < HID * N_CLASS; i += 256) {
        int c = i >> 6, k = i & 63;
        w2s[k * 41 + c] = W2[i] * 0.0625f;
    }
    int node = (blockIdx.x * 256 + t) >> 6;
    int lane = t & 63, wid = t >> 6;
    int e = lane >> 3, seg = lane & 7;
    int start = off[node];
    int nb = pdeg[node] >> 3;
    float a0=0,a1=0,a2=0,a3=0,a4=0,a5=0,a6=0,a7=0;
    int j = start;
    if (nb > 0) {
        int src = srow[j + e];
        uint2 raw = *(const uint2*)(o1q + ((size_t)src << 6) + (seg << 3));
        for (int b = 1; b < nb; ++b) {
            int nsrc = srow[j + 8 + e];
            uint2 nraw = *(const uint2*)(o1q + ((size_t)nsrc << 6) + (seg << 3));
            __builtin_amdgcn_sched_barrier(0);
            CONSUME8(raw);
            raw = nraw; j += 8;
        }
        CONSUME8(raw);
    }
    if (e == 0) {   // self term: + o1q[node]
        uint2 sraw = *(const uint2*)(o1q + ((size_t)node << 6) + (seg << 3));
        CONSUME8(sraw);
    }
#pragma unroll
    for (int m = 8; m < 64; m <<= 1) {
        a0 += __shfl_xor(a0, m); a1 += __shfl_xor(a1, m);
        a2 += __shfl_xor(a2, m); a3 += __shfl_xor(a3, m);
        a4 += __shfl_xor(a4, m); a5 += __shfl_xor(a5, m);
        a6 += __shfl_xor(a6, m); a7 += __shfl_xor(a7, m);
    }
    if (e == 0) {
        sh[wid][seg * 8 + 0] = a0; sh[wid][seg * 8 + 1] = a1;
        sh[wid][seg * 8 + 2] = a2; sh[wid][seg * 8 + 3] = a3;
        sh[wid][seg * 8 + 4] = a4; sh[wid][seg * 8 + 5] = a5;
        sh[wid][seg * 8 + 6] = a6; sh[wid][seg * 8 + 7] = a7;
    }
    __syncthreads();   // covers w2s staging + sh transpose
    bool act = lane < N_CLASS;
    int cl = act ? lane : N_CLASS - 1;
    float mv = 0.f;
#pragma unroll 8
    for (int k = 0; k < HID; ++k) {
        mv += sh[wid][k] * w2s[k * 41 + cl];   // sh broadcast, w2s conflict-free
    }
    float dc = dinv[node];
    float v = act ? (dc * mv + b2[lane]) : -1e30f;
    float m = v;
#pragma unroll
    for (int k = 1; k < 64; k <<= 1) {
        float o = __shfl_xor(m, k);
        m = o > m ? o : m;
    }
    float sv = act ? expf(v - m) : 0.f;
    float s = sv;
#pragma unroll
    for (int k = 1; k < 64; k <<= 1) s += __shfl_xor(s, k);
    float ls = logf(s);
    float av2 = v;
    int ai = act ? lane : 64;
#pragma unroll
    for (int k = 1; k < 64; k <<= 1) {
        float ov = __shfl_xor(av2, k);
        int oi = __shfl_xor(ai, k);
        if (ov > av2 || (ov == av2 && oi < ai)) { av2 = ov; ai = oi; }
    }
    if (act) {
        float lp = (v - m) - ls;
        float* logp = out;
        float* p = out + (size_t)N_NODES * N_CLASS;
        logp[(size_t)node * N_CLASS + lane] = lp;
        p[(size_t)node * N_CLASS + lane] = expf(lp);
    }
    if (lane == 0) ps[node] = (unsigned short)((y[node] << 8) | ai);
}

// ---------------- ratio over original edges (8 edges / iter, 16 gathers in flight) ----------------
__global__ __launch_bounds__(256) void k_ratio(const int* __restrict__ row, const int* __restrict__ col,
                                               const unsigned short* __restrict__ ps,
                                               unsigned int* __restrict__ cnt) {
    int i = blockIdx.x * 256 + threadIdx.x;
    int stride = gridDim.x * 256;
    unsigned int local = 0;
    for (int e8 = i; e8 < N_EDGES / 8; e8 += stride) {
        int4 ra = ((const int4*)row)[e8 * 2];
        int4 rb = ((const int4*)row)[e8 * 2 + 1];
        int4 ca = ((const int4*)col)[e8 * 2];
        int4 cb = ((const int4*)col)[e8 * 2 + 1];
        unsigned int pa[8], pb[8];
        pa[0] = ps[ra.x]; pa[1] = ps[ra.y]; pa[2] = ps[ra.z]; pa[3] = ps[ra.w];
        pa[4] = ps[rb.x]; pa[5] = ps[rb.y]; pa[6] = ps[rb.z]; pa[7] = ps[rb.w];
        pb[0] = ps[ca.x]; pb[1] = ps[ca.y]; pb[2] = ps[ca.z]; pb[3] = ps[ca.w];
        pb[4] = ps[cb.x]; pb[5] = ps[cb.y]; pb[6] = ps[cb.z]; pb[7] = ps[cb.w];
#pragma unroll
        for (int k = 0; k < 8; ++k) {
            bool sp = (pa[k] & 0xffu) == (pb[k] & 0xffu);
            bool sy = (pa[k] >> 8) == (pb[k] >> 8);
            local += (sp == sy) ? 1u : 0u;
        }
    }
    if (local) atomicAdd(cnt, local);
}

__global__ void k_fin(const unsigned int* __restrict__ cnt, float* __restrict__ out) {
    out[0] = (float)(*cnt) / (float)N_EDGES;
}

extern "C" void kernel_launch(void* const* d_in, const int* in_sizes, int n_in,
                              void* d_out, int out_size, void* d_ws, size_t ws_size,
                              hipStream_t stream) {
    const float* x  = (const float*)d_in[0];
    const int*   ei = (const int*)d_in[1];
    const int*   y  = (const int*)d_in[2];
    const float* W1 = (const float*)d_in[3];
    const float* b1 = (const float*)d_in[4];
    const float* W2 = (const float*)d_in[5];
    const float* b2 = (const float*)d_in[6];

    const int* row = ei;
    const int* col = ei + N_EDGES;

    float* ws = (float*)d_ws;
    // workspace layout (4B units); fp8 tables have N_NODES+1 rows (sentinel)
    unsigned char* h1q = (unsigned char*)ws;               // (N+1)*64 B -> 1.61M units
    unsigned char* o1q = (unsigned char*)(ws + 1700000);   // (N+1)*64 B
    float* dinv   = ws + 3400000;                   // N
    int*   pdeg   = (int*)(ws + 3500000);           // N
    int*   off    = (int*)(ws + 3600000);           // N
    int*   srow   = (int*)(ws + 3700000);           // padded CSR (~4.0M)
    int*   ghist  = (int*)(ws + 7800000);           // 512*256
    int*   goff   = (int*)(ws + 8000000);           // 512*256
    int*   bbase  = (int*)(ws + 8200000);           // 256
    int*   bend   = (int*)(ws + 8201000);           // 256
    unsigned short* ps = (unsigned short*)(ws + 8210000);  // N ushort
    unsigned int* cnt  = (unsigned int*)(ws + 8300000);
    unsigned int* epair = (unsigned int*)(ws + 8400000);   // E uint32

    float* out = (float*)d_out;

    hipMemsetAsync(cnt, 0, 4, stream);

    const int GEMM_GRID = (N_NODES + 127) / 128;
    const int AGG_GRID = (N_NODES * 64) / 256;      // exact: 25000

    k_A1<<<NBLK_A, 256, 0, stream>>>(col, ghist);
    k_A2<<<1, 256, 0, stream>>>(ghist, goff, bbase, bend);
    k_A3<<<NBLK_A, 256, 0, stream>>>(row, col, goff, epair);
    k_B<<<NBUCK, 256, 0, stream>>>(epair, bbase, bend, off, pdeg, dinv, srow);
    k_zrow<<<1, 128, 0, stream>>>(h1q, o1q);
    k_gemm<F_IN, HID, 128><<<GEMM_GRID, 256, 0, stream>>>(x, W1, dinv, h1q);
    k_agg1<<<AGG_GRID, 256, 0, stream>>>(off, pdeg, srow, dinv, h1q, b1, o1q);
    k_agg2<<<AGG_GRID, 256, 0, stream>>>(off, pdeg, srow, dinv, o1q, W2, b2, y, out, ps);
    k_ratio<<<2048, 256, 0, stream>>>(row, col, ps, cnt);
    k_fin<<<1, 1, 0, stream>>>(cnt, out + (size_t)2 * N_NODES * N_CLASS);
}

// Round 15
// 416.999 us; speedup vs baseline: 4.6563x; 1.0660x over previous
//
#include <hip/hip_runtime.h>

#define N_NODES 100000
#define N_EDGES 3200000
#define F_IN 128
#define HID 64
#define N_CLASS 40
#define ZROW N_NODES       // sentinel zero-row index

#define NBUCK 196          // ceil(100000/512)
#define BSHIFT 9
#define NBLK_A 512
#define CHUNK_A ((N_EDGES + NBLK_A - 1) / NBLK_A)

typedef float f32x2 __attribute__((ext_vector_type(2)));

static __device__ __forceinline__ unsigned char enc_fp8(float v) {
    int w = __builtin_amdgcn_cvt_pk_fp8_f32(v, v, 0, false);
    return (unsigned char)(w & 0xff);
}

// decode 8 fp8 (uint2) and accumulate into a0..a7
#define CONSUME8(RAW) do { \
    f32x2 f0 = __builtin_amdgcn_cvt_pk_f32_fp8((int)RAW.x, false); \
    f32x2 f1 = __builtin_amdgcn_cvt_pk_f32_fp8((int)RAW.x, true); \
    f32x2 f2 = __builtin_amdgcn_cvt_pk_f32_fp8((int)RAW.y, false); \
    f32x2 f3 = __builtin_amdgcn_cvt_pk_f32_fp8((int)RAW.y, true); \
    a0 += f0.x; a1 += f0.y; a2 += f1.x; a3 += f1.y; \
    a4 += f2.x; a5 += f2.y; a6 += f3.x; a7 += f3.y; } while (0)

// ---------------- Phase A1: per-block bucket histogram (transposed out) ----------------
__global__ __launch_bounds__(256) void k_A1(const int* __restrict__ col, int* __restrict__ ghistT) {
    __shared__ int hist[256];
    int t = threadIdx.x;
    hist[t] = 0;
    __syncthreads();
    int e0 = blockIdx.x * CHUNK_A;
    int e1 = e0 + CHUNK_A; if (e1 > N_EDGES) e1 = N_EDGES;
    for (int e = e0 + t; e < e1; e += 256) {
        atomicAdd(&hist[col[e] >> BSHIFT], 1);
    }
    __syncthreads();
    ghistT[t * NBLK_A + blockIdx.x] = hist[t];   // column-contiguous per bucket
}

// ---------------- Phase A2a: per-bucket scan over 512 A-blocks (256 blocks) ----------------
__global__ __launch_bounds__(256) void k_A2a(const int* __restrict__ ghistT, int* __restrict__ goffT,
                                             int* __restrict__ tot) {
    __shared__ int s[256];
    int b = blockIdx.x, t = threadIdx.x;
    int2 v = ((const int2*)(ghistT + b * NBLK_A))[t];
    int pair = v.x + v.y;
    s[t] = pair;
    __syncthreads();
    for (int d = 1; d < 256; d <<= 1) {
        int o = (t >= d) ? s[t - d] : 0;
        __syncthreads();
        s[t] += o;
        __syncthreads();
    }
    int incl = s[t];
    int excl = incl - pair;
    goffT[b * NBLK_A + 2 * t]     = excl;
    goffT[b * NBLK_A + 2 * t + 1] = excl + v.x;
    if (t == 255) tot[b] = incl;
}

// ---------------- Phase A2b: scan of 256 bucket totals ----------------
__global__ __launch_bounds__(256) void k_A2b(const int* __restrict__ tot, int* __restrict__ bbase,
                                             int* __restrict__ bend) {
    __shared__ int s[256];
    int t = threadIdx.x;
    int v = tot[t];
    s[t] = v;
    __syncthreads();
    for (int d = 1; d < 256; d <<= 1) {
        int o = (t >= d) ? s[t - d] : 0;
        __syncthreads();
        s[t] += o;
        __syncthreads();
    }
    bbase[t] = s[t] - v;
    bend[t] = s[t];
}

// ---------------- Phase A3: coalesced-reserved bucket scatter ----------------
__global__ __launch_bounds__(256) void k_A3(const int* __restrict__ row, const int* __restrict__ col,
                                            const int* __restrict__ goffT, const int* __restrict__ bbase,
                                            unsigned int* __restrict__ epair) {
    __shared__ int cur[256];
    int t = threadIdx.x;
    cur[t] = goffT[t * NBLK_A + blockIdx.x] + bbase[t];
    __syncthreads();
    int e0 = blockIdx.x * CHUNK_A;
    int e1 = e0 + CHUNK_A; if (e1 > N_EDGES) e1 = N_EDGES;
    for (int e = e0 + t; e < e1; e += 256) {
        int c = col[e];
        int pos = atomicAdd(&cur[c >> BSHIFT], 1);
        epair[pos] = ((unsigned int)(c & 511) << 17) | (unsigned int)row[e];
    }
}

// ---------------- Phase B: per-bucket CSR build, degrees padded to x8 ----------------
__global__ __launch_bounds__(256) void k_B(const unsigned int* __restrict__ epair,
                                           const int* __restrict__ bbase, const int* __restrict__ bend,
                                           int* __restrict__ off, int* __restrict__ pdeg,
                                           float* __restrict__ dinv, int* __restrict__ srow) {
    __shared__ int h[512];
    __shared__ int psc[256];
    int t = threadIdx.x;
    int b = blockIdx.x;
    int n0 = b << BSHIFT;
    int e0 = bbase[b], e1 = bend[b];
    int pbase = e0 + b * 4096;    // padded region base (<=4096 pad per bucket)
    h[t] = 0; h[t + 256] = 0;
    __syncthreads();
    for (int e = e0 + t; e < e1; e += 256) {
        atomicAdd(&h[epair[e] >> 17], 1);
    }
    __syncthreads();
    int a0 = h[2 * t], a1 = h[2 * t + 1];
    int p0 = (a0 + 7) & ~7, p1 = (a1 + 7) & ~7;
    psc[t] = p0 + p1;
    __syncthreads();
    for (int d = 1; d < 256; d <<= 1) {
        int o = (t >= d) ? psc[t - d] : 0;
        __syncthreads();
        psc[t] += o;
        __syncthreads();
    }
    int base0 = pbase + psc[t] - (p0 + p1);
    int base1 = base0 + p0;
    h[2 * t] = base0;
    h[2 * t + 1] = base1;
    int n = n0 + 2 * t;
    if (n < N_NODES) {
        off[n] = base0; pdeg[n] = p0; dinv[n] = rsqrtf((float)a0 + 1.0f);
        for (int p = a0; p < p0; ++p) srow[base0 + p] = ZROW;
    }
    if (n + 1 < N_NODES) {
        off[n + 1] = base1; pdeg[n + 1] = p1; dinv[n + 1] = rsqrtf((float)a1 + 1.0f);
        for (int p = a1; p < p1; ++p) srow[base1 + p] = ZROW;
    }
    __syncthreads();
    for (int e = e0 + t; e < e1; e += 256) {
        unsigned int k = epair[e];
        int c = k >> 17;
        int pos = atomicAdd(&h[c], 1);
        srow[pos] = (int)(k & 0x1FFFFu);
    }
}

// ---------------- zero the sentinel rows (fp8, 64 B each) ----------------
__global__ void k_zrow(unsigned char* __restrict__ h1q, unsigned char* __restrict__ o1q) {
    int t = threadIdx.x;
    if (t < 64) h1q[(size_t)ZROW * 64 + t] = 0;
    else        o1q[(size_t)ZROW * 64 + (t - 64)] = 0;
}

// ---------------- tiled dense GEMM (layer 1): O = fp8(scale[n]*(X @ W^T)) ----------------
template<int K, int C, int ROWS_PB>
__global__ __launch_bounds__(256, 4) void k_gemm(const float* __restrict__ X, const float* __restrict__ W,
                                                 const float* __restrict__ scale, unsigned char* __restrict__ O) {
    constexpr int PK = K + 4;
    __shared__ float ws[C * PK];
    __shared__ float xs[32 * PK];
    int t = threadIdx.x;
    for (int i4 = t; i4 < C * K / 4; i4 += 256) {
        int j = i4 / (K / 4);
        int k4 = i4 % (K / 4);
        float4 v = ((const float4*)W)[i4];
        *(float4*)&ws[j * PK + k4 * 4] = v;
    }
    int j = t & 63;
    int r0 = (t >> 6) * 8;
    int rowbase = blockIdx.x * ROWS_PB;
    for (int chunk = 0; chunk < ROWS_PB; chunk += 32) {
        int cb = rowbase + chunk;
        __syncthreads();
        for (int i4 = t; i4 < 32 * K / 4; i4 += 256) {
            int r = i4 / (K / 4);
            int k4 = i4 % (K / 4);
            int rr = cb + r;
            float4 v = make_float4(0.f, 0.f, 0.f, 0.f);
            if (rr < N_NODES) v = ((const float4*)X)[(size_t)rr * (K / 4) + k4];
            *(float4*)&xs[r * PK + k4 * 4] = v;
        }
        __syncthreads();
        if (j < C) {
            float acc[8] = {0.f, 0.f, 0.f, 0.f, 0.f, 0.f, 0.f, 0.f};
#pragma unroll 2
            for (int k4 = 0; k4 < K / 4; ++k4) {
                float4 wv = *(const float4*)&ws[j * PK + k4 * 4];
#pragma unroll
                for (int r = 0; r < 8; ++r) {
                    float4 xv = *(const float4*)&xs[(r0 + r) * PK + k4 * 4];
                    acc[r] += xv.x * wv.x + xv.y * wv.y + xv.z * wv.z + xv.w * wv.w;
                }
            }
#pragma unroll
            for (int r = 0; r < 8; ++r) {
                int rr = cb + r0 + r;
                if (rr < N_NODES) O[(size_t)rr * 64 + j] = enc_fp8(acc[r] * scale[rr]);
            }
        }
    }
}

// ---------------- layer-1 aggregation: fp8 gathers, srow window-shuffle ----------------
__global__ __launch_bounds__(256) void k_agg1(const int* __restrict__ off, const int* __restrict__ pdeg,
                                              const int* __restrict__ srow, const float* __restrict__ dinv,
                                              const unsigned char* __restrict__ h1q, const float* __restrict__ b1,
                                              unsigned char* __restrict__ o1q) {
    __shared__ __align__(16) float sh[4][64];
    int t = threadIdx.x;
    int node = (blockIdx.x * 256 + t) >> 6;
    int lane = t & 63, wid = t >> 6;
    int e = lane >> 3, seg = lane & 7;
    int start = off[node];
    int nb = pdeg[node] >> 3;
    float a0=0,a1=0,a2=0,a3=0,a4=0,a5=0,a6=0,a7=0;
    if (nb > 0) {
        int idxv = srow[start + lane];                     // 64 indices, coalesced
        int src = __shfl(idxv, e);
        uint2 raw = *(const uint2*)(h1q + (((unsigned)src << 6) | (unsigned)(seg << 3)));
        for (int b = 1; b < nb; ++b) {
            if ((b & 7) == 0) idxv = srow[start + (b << 3) + lane];   // next 64-index window
            int nsrc = __shfl(idxv, ((b & 7) << 3) | e);
            uint2 nraw = *(const uint2*)(h1q + (((unsigned)nsrc << 6) | (unsigned)(seg << 3)));
            __builtin_amdgcn_sched_barrier(0);
            CONSUME8(raw);
            raw = nraw;
        }
        CONSUME8(raw);
    }
    if (e == 0) {   // self term (counted once: only e-group 0)
        uint2 sraw = *(const uint2*)(h1q + (((unsigned)node << 6) | (unsigned)(seg << 3)));
        CONSUME8(sraw);
    }
#pragma unroll
    for (int m = 8; m < 64; m <<= 1) {
        a0 += __shfl_xor(a0, m); a1 += __shfl_xor(a1, m);
        a2 += __shfl_xor(a2, m); a3 += __shfl_xor(a3, m);
        a4 += __shfl_xor(a4, m); a5 += __shfl_xor(a5, m);
        a6 += __shfl_xor(a6, m); a7 += __shfl_xor(a7, m);
    }
    if (e == 0) {
        sh[wid][seg * 8 + 0] = a0; sh[wid][seg * 8 + 1] = a1;
        sh[wid][seg * 8 + 2] = a2; sh[wid][seg * 8 + 3] = a3;
        sh[wid][seg * 8 + 4] = a4; sh[wid][seg * 8 + 5] = a5;
        sh[wid][seg * 8 + 6] = a6; sh[wid][seg * 8 + 7] = a7;
    }
    __syncthreads();
    float dc = dinv[node];
    float v = dc * sh[wid][lane] + b1[lane];
    float r = v > 0.f ? v : 0.f;
    o1q[(size_t)node * 64 + lane] = enc_fp8(16.f * dc * r);   // x16: center in e4m3 range
}

// ---------------- layer-2: fp8 gather + fused W2 matvec (float4 LDS) + softmax ----------------
__global__ __launch_bounds__(256) void k_agg2(const int* __restrict__ off, const int* __restrict__ pdeg,
                                              const int* __restrict__ srow, const float* __restrict__ dinv,
                                              const unsigned char* __restrict__ o1q,
                                              const float* __restrict__ W2, const float* __restrict__ b2,
                                              const int* __restrict__ y,
                                              float* __restrict__ out, unsigned short* __restrict__ ps) {
    __shared__ __align__(16) float w2s[N_CLASS * 68];   // w2s[c*68+k] = W2[c][k]/16, 16B-aligned rows
    __shared__ __align__(16) float sh[4][64];
    int t = threadIdx.x;
    for (int i = t; i < HID * N_CLASS; i += 256) {
        int c = i >> 6, k = i & 63;
        w2s[c * 68 + k] = W2[i] * 0.0625f;
    }
    int node = (blockIdx.x * 256 + t) >> 6;
    int lane = t & 63, wid = t >> 6;
    int e = lane >> 3, seg = lane & 7;
    int start = off[node];
    int nb = pdeg[node] >> 3;
    float a0=0,a1=0,a2=0,a3=0,a4=0,a5=0,a6=0,a7=0;
    if (nb > 0) {
        int idxv = srow[start + lane];
        int src = __shfl(idxv, e);
        uint2 raw = *(const uint2*)(o1q + (((unsigned)src << 6) | (unsigned)(seg << 3)));
        for (int b = 1; b < nb; ++b) {
            if ((b & 7) == 0) idxv = srow[start + (b << 3) + lane];
            int nsrc = __shfl(idxv, ((b & 7) << 3) | e);
            uint2 nraw = *(const uint2*)(o1q + (((unsigned)nsrc << 6) | (unsigned)(seg << 3)));
            __builtin_amdgcn_sched_barrier(0);
            CONSUME8(raw);
            raw = nraw;
        }
        CONSUME8(raw);
    }
    if (e == 0) {   // self term: + o1q[node]
        uint2 sraw = *(const uint2*)(o1q + (((unsigned)node << 6) | (unsigned)(seg << 3)));
        CONSUME8(sraw);
    }
#pragma unroll
    for (int m = 8; m < 64; m <<= 1) {
        a0 += __shfl_xor(a0, m); a1 += __shfl_xor(a1, m);
        a2 += __shfl_xor(a2, m); a3 += __shfl_xor(a3, m);
        a4 += __shfl_xor(a4, m); a5 += __shfl_xor(a5, m);
        a6 += __shfl_xor(a6, m); a7 += __shfl_xor(a7, m);
    }
    if (e == 0) {
        sh[wid][seg * 8 + 0] = a0; sh[wid][seg * 8 + 1] = a1;
        sh[wid][seg * 8 + 2] = a2; sh[wid][seg * 8 + 3] = a3;
        sh[wid][seg * 8 + 4] = a4; sh[wid][seg * 8 + 5] = a5;
        sh[wid][seg * 8 + 6] = a6; sh[wid][seg * 8 + 7] = a7;
    }
    __syncthreads();   // covers w2s staging + sh transpose
    bool act = lane < N_CLASS;
    int cl = act ? lane : N_CLASS - 1;
    float mv = 0.f;
#pragma unroll
    for (int k4 = 0; k4 < HID / 4; ++k4) {
        float4 sv = *(const float4*)&sh[wid][k4 * 4];         // broadcast read
        float4 wv = *(const float4*)&w2s[cl * 68 + k4 * 4];   // b128, <=2-way overlap
        mv += sv.x * wv.x + sv.y * wv.y + sv.z * wv.z + sv.w * wv.w;
    }
    float dc = dinv[node];
    float v = act ? (dc * mv + b2[lane]) : -1e30f;
    float m = v;
#pragma unroll
    for (int k = 1; k < 64; k <<= 1) {
        float o = __shfl_xor(m, k);
        m = o > m ? o : m;
    }
    float sv2 = act ? expf(v - m) : 0.f;
    float s = sv2;
#pragma unroll
    for (int k = 1; k < 64; k <<= 1) s += __shfl_xor(s, k);
    float ls = logf(s);
    float av2 = v;
    int ai = act ? lane : 64;
#pragma unroll
    for (int k = 1; k < 64; k <<= 1) {
        float ov = __shfl_xor(av2, k);
        int oi = __shfl_xor(ai, k);
        if (ov > av2 || (ov == av2 && oi < ai)) { av2 = ov; ai = oi; }
    }
    if (act) {
        float lp = (v - m) - ls;
        float* logp = out;
        float* p = out + (size_t)N_NODES * N_CLASS;
        logp[(size_t)node * N_CLASS + lane] = lp;
        p[(size_t)node * N_CLASS + lane] = expf(lp);
    }
    if (lane == 0) ps[node] = (unsigned short)((y[node] << 8) | ai);
}

// ---------------- ratio over original edges (8 edges / iter) ----------------
__global__ __launch_bounds__(256) void k_ratio(const int* __restrict__ row, const int* __restrict__ col,
                                               const unsigned short* __restrict__ ps,
                                               unsigned int* __restrict__ cnt) {
    int i = blockIdx.x * 256 + threadIdx.x;
    int stride = gridDim.x * 256;
    unsigned int local = 0;
    for (int e8 = i; e8 < N_EDGES / 8; e8 += stride) {
        int4 ra = ((const int4*)row)[e8 * 2];
        int4 rb = ((const int4*)row)[e8 * 2 + 1];
        int4 ca = ((const int4*)col)[e8 * 2];
        int4 cb = ((const int4*)col)[e8 * 2 + 1];
        unsigned int pa[8], pb[8];
        pa[0] = ps[ra.x]; pa[1] = ps[ra.y]; pa[2] = ps[ra.z]; pa[3] = ps[ra.w];
        pa[4] = ps[rb.x]; pa[5] = ps[rb.y]; pa[6] = ps[rb.z]; pa[7] = ps[rb.w];
        pb[0] = ps[ca.x]; pb[1] = ps[ca.y]; pb[2] = ps[ca.z]; pb[3] = ps[ca.w];
        pb[4] = ps[cb.x]; pb[5] = ps[cb.y]; pb[6] = ps[cb.z]; pb[7] = ps[cb.w];
#pragma unroll
        for (int k = 0; k < 8; ++k) {
            bool sp = (pa[k] & 0xffu) == (pb[k] & 0xffu);
            bool sy = (pa[k] >> 8) == (pb[k] >> 8);
            local += (sp == sy) ? 1u : 0u;
        }
    }
    if (local) atomicAdd(cnt, local);
}

__global__ void k_fin(const unsigned int* __restrict__ cnt, float* __restrict__ out) {
    out[0] = (float)(*cnt) / (float)N_EDGES;
}

extern "C" void kernel_launch(void* const* d_in, const int* in_sizes, int n_in,
                              void* d_out, int out_size, void* d_ws, size_t ws_size,
                              hipStream_t stream) {
    const float* x  = (const float*)d_in[0];
    const int*   ei = (const int*)d_in[1];
    const int*   y  = (const int*)d_in[2];
    const float* W1 = (const float*)d_in[3];
    const float* b1 = (const float*)d_in[4];
    const float* W2 = (const float*)d_in[5];
    const float* b2 = (const float*)d_in[6];

    const int* row = ei;
    const int* col = ei + N_EDGES;

    float* ws = (float*)d_ws;
    // workspace layout (4B units); fp8 tables have N_NODES+1 rows (sentinel)
    unsigned char* h1q = (unsigned char*)ws;               // (N+1)*64 B
    unsigned char* o1q = (unsigned char*)(ws + 1700000);   // (N+1)*64 B
    float* dinv   = ws + 3400000;                   // N
    int*   pdeg   = (int*)(ws + 3500000);           // N
    int*   off    = (int*)(ws + 3600000);           // N
    int*   srow   = (int*)(ws + 3700000);           // padded CSR (~4.0M)
    int*   ghistT = (int*)(ws + 7800000);           // 256*512 (bucket-major)
    int*   goffT  = (int*)(ws + 8000000);           // 256*512
    int*   tot    = (int*)(ws + 8150000);           // 256
    int*   bbase  = (int*)(ws + 8200000);           // 256
    int*   bend   = (int*)(ws + 8201000);           // 256
    unsigned short* ps = (unsigned short*)(ws + 8210000);  // N ushort
    unsigned int* cnt  = (unsigned int*)(ws + 8300000);
    unsigned int* epair = (unsigned int*)(ws + 8400000);   // E uint32

    float* out = (float*)d_out;

    hipMemsetAsync(cnt, 0, 4, stream);

    const int GEMM_GRID = (N_NODES + 127) / 128;
    const int AGG_GRID = (N_NODES * 64) / 256;      // exact: 25000

    k_A1<<<NBLK_A, 256, 0, stream>>>(col, ghistT);
    k_A2a<<<256, 256, 0, stream>>>(ghistT, goffT, tot);
    k_A2b<<<1, 256, 0, stream>>>(tot, bbase, bend);
    k_A3<<<NBLK_A, 256, 0, stream>>>(row, col, goffT, bbase, epair);
    k_B<<<NBUCK, 256, 0, stream>>>(epair, bbase, bend, off, pdeg, dinv, srow);
    k_zrow<<<1, 128, 0, stream>>>(h1q, o1q);
    k_gemm<F_IN, HID, 128><<<GEMM_GRID, 256, 0, stream>>>(x, W1, dinv, h1q);
    k_agg1<<<AGG_GRID, 256, 0, stream>>>(off, pdeg, srow, dinv, h1q, b1, o1q);
    k_agg2<<<AGG_GRID, 256, 0, stream>>>(off, pdeg, srow, dinv, o1q, W2, b2, y, out, ps);
    k_ratio<<<2048, 256, 0, stream>>>(row, col, ps, cnt);
    k_fin<<<1, 1, 0, stream>>>(cnt, out + (size_t)2 * N_NODES * N_CLASS);
}

// Round 16
// 411.065 us; speedup vs baseline: 4.7235x; 1.0144x over previous
//
#include <hip/hip_runtime.h>

#define N_NODES 100000
#define N_EDGES 3200000
#define F_IN 128
#define HID 64
#define N_CLASS 40
#define ZROW N_NODES       // sentinel zero-row index

#define NBUCK 196          // ceil(100000/512)
#define BSHIFT 9
#define NBLK_A 512
#define CHUNK_A ((N_EDGES + NBLK_A - 1) / NBLK_A)

typedef float f32x2 __attribute__((ext_vector_type(2)));

static __device__ __forceinline__ unsigned char enc_fp8(float v) {
    int w = __builtin_amdgcn_cvt_pk_fp8_f32(v, v, 0, false);
    return (unsigned char)(w & 0xff);
}

static __device__ __forceinline__ uint2 gat(const unsigned char* base, int srcrow, int seg) {
    return *(const uint2*)(base + (((unsigned)srcrow << 6) | (unsigned)(seg << 3)));
}

// decode 8 fp8 (uint2) and accumulate into a0..a7
#define CONSUME8(RAW) do { \
    f32x2 f0 = __builtin_amdgcn_cvt_pk_f32_fp8((int)RAW.x, false); \
    f32x2 f1 = __builtin_amdgcn_cvt_pk_f32_fp8((int)RAW.x, true); \
    f32x2 f2 = __builtin_amdgcn_cvt_pk_f32_fp8((int)RAW.y, false); \
    f32x2 f3 = __builtin_amdgcn_cvt_pk_f32_fp8((int)RAW.y, true); \
    a0 += f0.x; a1 += f0.y; a2 += f1.x; a3 += f1.y; \
    a4 += f2.x; a5 += f2.y; a6 += f3.x; a7 += f3.y; } while (0)

// 6-deep pipelined gather slot: issue iter (bb+6+s), consume register G (iter bb+s)
#define SLOT(s, G) { \
    int ib = bb + 6 + s; \
    if (((ib & 7) == 0) && (ib < nb)) idxv = srow[start + (ib << 3) + lane]; \
    int srcr = (ib < nb) ? __shfl(idxv, ((ib & 7) << 3) | e) : ZROW; \
    uint2 ng = gat(gsrc, srcr, seg); \
    __builtin_amdgcn_sched_barrier(0); \
    CONSUME8(G); \
    G = ng; }

// gather phase shared by both aggs: 8 accumulators summed over all in-edges
#define GATHER_PHASE(TBL) \
    float a0=0,a1=0,a2=0,a3=0,a4=0,a5=0,a6=0,a7=0; \
    { \
        const unsigned char* gsrc = TBL; \
        int nb = pdeg[node] >> 3; \
        if (nb > 0) { \
            int idxv = srow[start + lane]; \
            int s0 = (0 < nb) ? __shfl(idxv, 0  | e) : ZROW; \
            int s1 = (1 < nb) ? __shfl(idxv, 8  | e) : ZROW; \
            int s2 = (2 < nb) ? __shfl(idxv, 16 | e) : ZROW; \
            int s3 = (3 < nb) ? __shfl(idxv, 24 | e) : ZROW; \
            int s4 = (4 < nb) ? __shfl(idxv, 32 | e) : ZROW; \
            int s5 = (5 < nb) ? __shfl(idxv, 40 | e) : ZROW; \
            uint2 g0 = gat(gsrc, s0, seg); \
            uint2 g1 = gat(gsrc, s1, seg); \
            uint2 g2 = gat(gsrc, s2, seg); \
            uint2 g3 = gat(gsrc, s3, seg); \
            uint2 g4 = gat(gsrc, s4, seg); \
            uint2 g5 = gat(gsrc, s5, seg); \
            for (int bb = 0; bb < nb; bb += 6) { \
                SLOT(0, g0) SLOT(1, g1) SLOT(2, g2) \
                SLOT(3, g3) SLOT(4, g4) SLOT(5, g5) \
            } \
        } \
        if (e == 0) {  /* self term, counted once */ \
            uint2 sraw = gat(gsrc, node, seg); \
            CONSUME8(sraw); \
        } \
    } \
    _Pragma("unroll") \
    for (int m = 8; m < 64; m <<= 1) { \
        a0 += __shfl_xor(a0, m); a1 += __shfl_xor(a1, m); \
        a2 += __shfl_xor(a2, m); a3 += __shfl_xor(a3, m); \
        a4 += __shfl_xor(a4, m); a5 += __shfl_xor(a5, m); \
        a6 += __shfl_xor(a6, m); a7 += __shfl_xor(a7, m); \
    } \
    if (e == 0) { \
        sh[wid][seg * 8 + 0] = a0; sh[wid][seg * 8 + 1] = a1; \
        sh[wid][seg * 8 + 2] = a2; sh[wid][seg * 8 + 3] = a3; \
        sh[wid][seg * 8 + 4] = a4; sh[wid][seg * 8 + 5] = a5; \
        sh[wid][seg * 8 + 6] = a6; sh[wid][seg * 8 + 7] = a7; \
    }

// ---------------- Phase A1: per-block bucket histogram (transposed out) ----------------
__global__ __launch_bounds__(256) void k_A1(const int* __restrict__ col, int* __restrict__ ghistT) {
    __shared__ int hist[256];
    int t = threadIdx.x;
    hist[t] = 0;
    __syncthreads();
    int e0 = blockIdx.x * CHUNK_A;
    int e1 = e0 + CHUNK_A; if (e1 > N_EDGES) e1 = N_EDGES;
    for (int e = e0 + t; e < e1; e += 256) {
        atomicAdd(&hist[col[e] >> BSHIFT], 1);
    }
    __syncthreads();
    ghistT[t * NBLK_A + blockIdx.x] = hist[t];   // column-contiguous per bucket
}

// ---------------- Phase A2a: per-bucket scan over 512 A-blocks (256 blocks) ----------------
__global__ __launch_bounds__(256) void k_A2a(const int* __restrict__ ghistT, int* __restrict__ goffT,
                                             int* __restrict__ tot) {
    __shared__ int s[256];
    int b = blockIdx.x, t = threadIdx.x;
    int2 v = ((const int2*)(ghistT + b * NBLK_A))[t];
    int pair = v.x + v.y;
    s[t] = pair;
    __syncthreads();
    for (int d = 1; d < 256; d <<= 1) {
        int o = (t >= d) ? s[t - d] : 0;
        __syncthreads();
        s[t] += o;
        __syncthreads();
    }
    int incl = s[t];
    int excl = incl - pair;
    goffT[b * NBLK_A + 2 * t]     = excl;
    goffT[b * NBLK_A + 2 * t + 1] = excl + v.x;
    if (t == 255) tot[b] = incl;
}

// ---------------- Phase A2b: scan of 256 bucket totals (+ zero sentinel rows) ----------------
__global__ __launch_bounds__(256) void k_A2b(const int* __restrict__ tot, int* __restrict__ bbase,
                                             int* __restrict__ bend,
                                             unsigned char* __restrict__ h1q,
                                             unsigned char* __restrict__ o1q) {
    __shared__ int s[256];
    int t = threadIdx.x;
    int v = tot[t];
    s[t] = v;
    __syncthreads();
    for (int d = 1; d < 256; d <<= 1) {
        int o = (t >= d) ? s[t - d] : 0;
        __syncthreads();
        s[t] += o;
        __syncthreads();
    }
    bbase[t] = s[t] - v;
    bend[t] = s[t];
    if (t < 64) h1q[(size_t)ZROW * 64 + t] = 0;
    else if (t < 128) o1q[(size_t)ZROW * 64 + (t - 64)] = 0;
}

// ---------------- Phase A3: coalesced-reserved bucket scatter ----------------
__global__ __launch_bounds__(256) void k_A3(const int* __restrict__ row, const int* __restrict__ col,
                                            const int* __restrict__ goffT, const int* __restrict__ bbase,
                                            unsigned int* __restrict__ epair) {
    __shared__ int cur[256];
    int t = threadIdx.x;
    cur[t] = goffT[t * NBLK_A + blockIdx.x] + bbase[t];
    __syncthreads();
    int e0 = blockIdx.x * CHUNK_A;
    int e1 = e0 + CHUNK_A; if (e1 > N_EDGES) e1 = N_EDGES;
    for (int e = e0 + t; e < e1; e += 256) {
        int c = col[e];
        int pos = atomicAdd(&cur[c >> BSHIFT], 1);
        epair[pos] = ((unsigned int)(c & 511) << 17) | (unsigned int)row[e];
    }
}

// ---------------- Phase B: per-bucket CSR build, degrees padded to x8 ----------------
__global__ __launch_bounds__(256) void k_B(const unsigned int* __restrict__ epair,
                                           const int* __restrict__ bbase, const int* __restrict__ bend,
                                           int* __restrict__ off, int* __restrict__ pdeg,
                                           float* __restrict__ dinv, int* __restrict__ srow) {
    __shared__ int h[512];
    __shared__ int psc[256];
    int t = threadIdx.x;
    int b = blockIdx.x;
    int n0 = b << BSHIFT;
    int e0 = bbase[b], e1 = bend[b];
    int pbase = e0 + b * 4096;    // padded region base (<=4096 pad per bucket)
    h[t] = 0; h[t + 256] = 0;
    __syncthreads();
    for (int e = e0 + t; e < e1; e += 256) {
        atomicAdd(&h[epair[e] >> 17], 1);
    }
    __syncthreads();
    int a0 = h[2 * t], a1 = h[2 * t + 1];
    int p0 = (a0 + 7) & ~7, p1 = (a1 + 7) & ~7;
    psc[t] = p0 + p1;
    __syncthreads();
    for (int d = 1; d < 256; d <<= 1) {
        int o = (t >= d) ? psc[t - d] : 0;
        __syncthreads();
        psc[t] += o;
        __syncthreads();
    }
    int base0 = pbase + psc[t] - (p0 + p1);
    int base1 = base0 + p0;
    h[2 * t] = base0;
    h[2 * t + 1] = base1;
    int n = n0 + 2 * t;
    if (n < N_NODES) {
        off[n] = base0; pdeg[n] = p0; dinv[n] = rsqrtf((float)a0 + 1.0f);
        for (int p = a0; p < p0; ++p) srow[base0 + p] = ZROW;
    }
    if (n + 1 < N_NODES) {
        off[n + 1] = base1; pdeg[n + 1] = p1; dinv[n + 1] = rsqrtf((float)a1 + 1.0f);
        for (int p = a1; p < p1; ++p) srow[base1 + p] = ZROW;
    }
    __syncthreads();
    for (int e = e0 + t; e < e1; e += 256) {
        unsigned int k = epair[e];
        int c = k >> 17;
        int pos = atomicAdd(&h[c], 1);
        srow[pos] = (int)(k & 0x1FFFFu);
    }
}

// ---------------- tiled dense GEMM (layer 1): O = fp8(scale[n]*(X @ W^T)) ----------------
template<int K, int C, int ROWS_PB>
__global__ __launch_bounds__(256, 4) void k_gemm(const float* __restrict__ X, const float* __restrict__ W,
                                                 const float* __restrict__ scale, unsigned char* __restrict__ O) {
    constexpr int PK = K + 4;
    __shared__ float ws[C * PK];
    __shared__ float xs[32 * PK];
    int t = threadIdx.x;
    for (int i4 = t; i4 < C * K / 4; i4 += 256) {
        int j = i4 / (K / 4);
        int k4 = i4 % (K / 4);
        float4 v = ((const float4*)W)[i4];
        *(float4*)&ws[j * PK + k4 * 4] = v;
    }
    int j = t & 63;
    int r0 = (t >> 6) * 8;
    int rowbase = blockIdx.x * ROWS_PB;
    for (int chunk = 0; chunk < ROWS_PB; chunk += 32) {
        int cb = rowbase + chunk;
        __syncthreads();
        for (int i4 = t; i4 < 32 * K / 4; i4 += 256) {
            int r = i4 / (K / 4);
            int k4 = i4 % (K / 4);
            int rr = cb + r;
            float4 v = make_float4(0.f, 0.f, 0.f, 0.f);
            if (rr < N_NODES) v = ((const float4*)X)[(size_t)rr * (K / 4) + k4];
            *(float4*)&xs[r * PK + k4 * 4] = v;
        }
        __syncthreads();
        if (j < C) {
            float acc[8] = {0.f, 0.f, 0.f, 0.f, 0.f, 0.f, 0.f, 0.f};
#pragma unroll 2
            for (int k4 = 0; k4 < K / 4; ++k4) {
                float4 wv = *(const float4*)&ws[j * PK + k4 * 4];
#pragma unroll
                for (int r = 0; r < 8; ++r) {
                    float4 xv = *(const float4*)&xs[(r0 + r) * PK + k4 * 4];
                    acc[r] += xv.x * wv.x + xv.y * wv.y + xv.z * wv.z + xv.w * wv.w;
                }
            }
#pragma unroll
            for (int r = 0; r < 8; ++r) {
                int rr = cb + r0 + r;
                if (rr < N_NODES) O[(size_t)rr * 64 + j] = enc_fp8(acc[r] * scale[rr]);
            }
        }
    }
}

// ---------------- layer-1 aggregation: 6-deep fp8 gather pipeline ----------------
__global__ __launch_bounds__(256) void k_agg1(const int* __restrict__ off, const int* __restrict__ pdeg,
                                              const int* __restrict__ srow, const float* __restrict__ dinv,
                                              const unsigned char* __restrict__ h1q, const float* __restrict__ b1,
                                              unsigned char* __restrict__ o1q) {
    __shared__ __align__(16) float sh[4][64];
    int t = threadIdx.x;
    int node = (blockIdx.x * 256 + t) >> 6;
    int lane = t & 63, wid = t >> 6;
    int e = lane >> 3, seg = lane & 7;
    int start = off[node];
    GATHER_PHASE(h1q)
    __syncthreads();
    float dc = dinv[node];
    float v = dc * sh[wid][lane] + b1[lane];
    float r = v > 0.f ? v : 0.f;
    o1q[(size_t)node * 64 + lane] = enc_fp8(16.f * dc * r);   // x16: center in e4m3 range
}

// ---------------- layer-2: 6-deep fp8 gather + fused W2 matvec + softmax ----------------
__global__ __launch_bounds__(256) void k_agg2(const int* __restrict__ off, const int* __restrict__ pdeg,
                                              const int* __restrict__ srow, const float* __restrict__ dinv,
                                              const unsigned char* __restrict__ o1q,
                                              const float* __restrict__ W2, const float* __restrict__ b2,
                                              const int* __restrict__ y,
                                              float* __restrict__ out, unsigned short* __restrict__ ps) {
    __shared__ __align__(16) float w2s[N_CLASS * 68];   // w2s[c*68+k] = W2[c][k]/16
    __shared__ __align__(16) float sh[4][64];
    int t = threadIdx.x;
    for (int i = t; i < HID * N_CLASS; i += 256) {
        int c = i >> 6, k = i & 63;
        w2s[c * 68 + k] = W2[i] * 0.0625f;
    }
    int node = (blockIdx.x * 256 + t) >> 6;
    int lane = t & 63, wid = t >> 6;
    int e = lane >> 3, seg = lane & 7;
    int start = off[node];
    GATHER_PHASE(o1q)
    __syncthreads();   // covers w2s staging + sh transpose
    bool act = lane < N_CLASS;
    int cl = act ? lane : N_CLASS - 1;
    float mv = 0.f;
#pragma unroll
    for (int k4 = 0; k4 < HID / 4; ++k4) {
        float4 sv = *(const float4*)&sh[wid][k4 * 4];         // broadcast read
        float4 wv = *(const float4*)&w2s[cl * 68 + k4 * 4];   // b128, <=2-way overlap
        mv += sv.x * wv.x + sv.y * wv.y + sv.z * wv.z + sv.w * wv.w;
    }
    float dc = dinv[node];
    float v = act ? (dc * mv + b2[lane]) : -1e30f;
    float m = v;
#pragma unroll
    for (int k = 1; k < 64; k <<= 1) {
        float o = __shfl_xor(m, k);
        m = o > m ? o : m;
    }
    float sv2 = act ? expf(v - m) : 0.f;
    float s = sv2;
#pragma unroll
    for (int k = 1; k < 64; k <<= 1) s += __shfl_xor(s, k);
    float ls = logf(s);
    float av2 = v;
    int ai = act ? lane : 64;
#pragma unroll
    for (int k = 1; k < 64; k <<= 1) {
        float ov = __shfl_xor(av2, k);
        int oi = __shfl_xor(ai, k);
        if (ov > av2 || (ov == av2 && oi < ai)) { av2 = ov; ai = oi; }
    }
    if (act) {
        float lp = (v - m) - ls;
        float* logp = out;
        float* p = out + (size_t)N_NODES * N_CLASS;
        logp[(size_t)node * N_CLASS + lane] = lp;
        p[(size_t)node * N_CLASS + lane] = expf(lp);
    }
    if (lane == 0) ps[node] = (unsigned short)((y[node] << 8) | ai);
}

// ---------------- ratio over original edges (8 edges / iter) ----------------
__global__ __launch_bounds__(256) void k_ratio(const int* __restrict__ row, const int* __restrict__ col,
                                               const unsigned short* __restrict__ ps,
                                               unsigned int* __restrict__ cnt) {
    int i = blockIdx.x * 256 + threadIdx.x;
    int stride = gridDim.x * 256;
    unsigned int local = 0;
    for (int e8 = i; e8 < N_EDGES / 8; e8 += stride) {
        int4 ra = ((const int4*)row)[e8 * 2];
        int4 rb = ((const int4*)row)[e8 * 2 + 1];
        int4 ca = ((const int4*)col)[e8 * 2];
        int4 cb = ((const int4*)col)[e8 * 2 + 1];
        unsigned int pa[8], pb[8];
        pa[0] = ps[ra.x]; pa[1] = ps[ra.y]; pa[2] = ps[ra.z]; pa[3] = ps[ra.w];
        pa[4] = ps[rb.x]; pa[5] = ps[rb.y]; pa[6] = ps[rb.z]; pa[7] = ps[rb.w];
        pb[0] = ps[ca.x]; pb[1] = ps[ca.y]; pb[2] = ps[ca.z]; pb[3] = ps[ca.w];
        pb[4] = ps[cb.x]; pb[5] = ps[cb.y]; pb[6] = ps[cb.z]; pb[7] = ps[cb.w];
#pragma unroll
        for (int k = 0; k < 8; ++k) {
            bool sp = (pa[k] & 0xffu) == (pb[k] & 0xffu);
            bool sy = (pa[k] >> 8) == (pb[k] >> 8);
            local += (sp == sy) ? 1u : 0u;
        }
    }
    if (local) atomicAdd(cnt, local);
}

__global__ void k_fin(const unsigned int* __restrict__ cnt, float* __restrict__ out) {
    out[0] = (float)(*cnt) / (float)N_EDGES;
}

extern "C" void kernel_launch(void* const* d_in, const int* in_sizes, int n_in,
                              void* d_out, int out_size, void* d_ws, size_t ws_size,
                              hipStream_t stream) {
    const float* x  = (const float*)d_in[0];
    const int*   ei = (const int*)d_in[1];
    const int*   y  = (const int*)d_in[2];
    const float* W1 = (const float*)d_in[3];
    const float* b1 = (const float*)d_in[4];
    const float* W2 = (const float*)d_in[5];
    const float* b2 = (const float*)d_in[6];

    const int* row = ei;
    const int* col = ei + N_EDGES;

    float* ws = (float*)d_ws;
    // workspace layout (4B units); fp8 tables have N_NODES+1 rows (sentinel)
    unsigned char* h1q = (unsigned char*)ws;               // (N+1)*64 B
    unsigned char* o1q = (unsigned char*)(ws + 1700000);   // (N+1)*64 B
    float* dinv   = ws + 3400000;                   // N
    int*   pdeg   = (int*)(ws + 3500000);           // N
    int*   off    = (int*)(ws + 3600000);           // N
    int*   srow   = (int*)(ws + 3700000);           // padded CSR (~4.0M) + slack
    int*   ghistT = (int*)(ws + 7800000);           // 256*512 (bucket-major)
    int*   goffT  = (int*)(ws + 8000000);           // 256*512
    int*   tot    = (int*)(ws + 8150000);           // 256
    int*   bbase  = (int*)(ws + 8200000);           // 256
    int*   bend   = (int*)(ws + 8201000);           // 256
    unsigned short* ps = (unsigned short*)(ws + 8210000);  // N ushort
    unsigned int* cnt  = (unsigned int*)(ws + 8300000);
    unsigned int* epair = (unsigned int*)(ws + 8400000);   // E uint32

    float* out = (float*)d_out;

    hipMemsetAsync(cnt, 0, 4, stream);

    const int GEMM_GRID = (N_NODES + 127) / 128;
    const int AGG_GRID = (N_NODES * 64) / 256;      // exact: 25000

    k_A1<<<NBLK_A, 256, 0, stream>>>(col, ghistT);
    k_A2a<<<256, 256, 0, stream>>>(ghistT, goffT, tot);
    k_A2b<<<1, 256, 0, stream>>>(tot, bbase, bend, h1q, o1q);
    k_A3<<<NBLK_A, 256, 0, stream>>>(row, col, goffT, bbase, epair);
    k_B<<<NBUCK, 256, 0, stream>>>(epair, bbase, bend, off, pdeg, dinv, srow);
    k_gemm<F_IN, HID, 128><<<GEMM_GRID, 256, 0, stream>>>(x, W1, dinv, h1q);
    k_agg1<<<AGG_GRID, 256, 0, stream>>>(off, pdeg, srow, dinv, h1q, b1, o1q);
    k_agg2<<<AGG_GRID, 256, 0, stream>>>(off, pdeg, srow, dinv, o1q, W2, b2, y, out, ps);
    k_ratio<<<2048, 256, 0, stream>>>(row, col, ps, cnt);
    k_fin<<<1, 1, 0, stream>>>(cnt, out + (size_t)2 * N_NODES * N_CLASS);
}